// Round 18
// baseline (228.103 us; speedup 1.0000x reference)
//
#include <hip/hip_runtime.h>
#include <hip/hip_bf16.h>
#include <math.h>

// CrossTransformerBlock3D: D=H=W=32, DIM=192, HEADS=12, HD=16, WS=2x2x2
// bf16-MFMA everywhere. LN1 fused into merged Q+KV GEMM prologue, LN2 into
// P-GEMM epilogue. Q pre-scaled by 0.25*log2e so attn softmax is exp2(s).
// GEMMs: LDS-staged 72KB B-panel (r11 template; MT=2 on P/MLP).
// Attn: PERSISTENT blocks (1792 = 7/CU), each looping a contiguous XCD-local
// chunk of (window, head-pair) items -- kills block churn, overlaps item i+1
// gathers with item i PV. QK^T 32x32x16, 16B V path, PV 16x16x32 tr-read.

#define TOK 32768
#define NWIN 4096
#define AITEMS (NWIN * 6)
#define ABLOCKS 1792

typedef float f32x4 __attribute__((ext_vector_type(4)));
typedef float f32x16 __attribute__((ext_vector_type(16)));
typedef short bf16x8 __attribute__((ext_vector_type(8)));
typedef short bf16x4 __attribute__((ext_vector_type(4)));

static __device__ __forceinline__ short f2bf(float x) {
  __hip_bfloat16 h = __float2bfloat16(x);
  return __builtin_bit_cast(short, h);
}

enum { EP_RESID_LN = 2, EP_GELU = 3, EP_RESID = 4 };

// ---------------- fused prep: weight packs + neighborhood idx + bkv cast -----
static __device__ __forceinline__ void pack_one(const float* __restrict__ W,
                                                short* __restrict__ dst,
                                                int K, int N, int blk, int lane) {
  int KS = K / 32;
  int ks = blk % KS, c = blk / KS;
  int col = c * 16 + (lane & 15);
  int krow = ks * 32 + (lane >> 4) * 8;
  bf16x8 v;
#pragma unroll
  for (int j = 0; j < 8; ++j) v[j] = f2bf(W[(size_t)(krow + j) * N + col]);
  *(bf16x8*)(dst + ((size_t)blk * 64 + lane) * 8) = v;
}

__global__ __launch_bounds__(256) void prep_kernel(
    const float* __restrict__ Wq, const float* __restrict__ Wkv,
    const float* __restrict__ Wp, const float* __restrict__ W1,
    const float* __restrict__ W2, const float* __restrict__ bkv,
    short* __restrict__ wq_p, short* __restrict__ wkv_p, short* __restrict__ wp_p,
    short* __restrict__ w1_p, short* __restrict__ w2_p,
    short* __restrict__ kext, short* __restrict__ vext,
    int* __restrict__ gIdx) {
  int bid = blockIdx.x;
  int tid = threadIdx.x;
  if (bid < 144) {  // 4 pack-units per block
    int pb = bid * 4 + (tid >> 6);
    int lane = tid & 63;
    if (pb < 72)        pack_one(Wq,  wq_p,  192, 192, pb,       lane);
    else if (pb < 216)  pack_one(Wkv, wkv_p, 192, 384, pb - 72,  lane);
    else if (pb < 288)  pack_one(Wp,  wp_p,  192, 192, pb - 216, lane);
    else if (pb < 432)  pack_one(W1,  w1_p,  192, 384, pb - 288, lane);
    else                pack_one(W2,  w2_p,  384, 192, pb - 432, lane);
  } else if (bid < 144 + NWIN) {  // neighborhood idx -> BYTE offsets
    int w = bid - 144;
    int m = tid;
    if (m >= 224) return;
    int ww = w & 15, wh = (w >> 4) & 15, wd = w >> 8;
    int t = TOK;  // sentinel row = bkv projection
    if (m < 216) {
      int lw = m & 1;  int t1 = m >> 1;
      int dk = t1 % 3; int t2 = t1 / 3;
      int lh = t2 & 1; int t3 = t2 >> 1;
      int dj = t3 % 3; int t4 = t3 / 3;
      int ld = t4 & 1; int di = t4 >> 1;
      int nwd = wd + di - 1, nwh = wh + dj - 1, nww = ww + dk - 1;
      int slab = di * 9 + dj * 3 + dk;
      if (nwd >= 0 && nwd <= 15 && nwh >= 0 && nwh <= 15 && nww >= 0 && nww <= 15 && slab != 20) {
        t = ((nwd * 2 + ld) * 32 + (nwh * 2 + lh)) * 32 + (nww * 2 + lw);
      }
    }
    gIdx[w * 224 + m] = t * 384;  // byte offset into K/V (192 ch * 2B)
  } else {  // bkv extension rows
    if (tid < 192)      kext[tid] = f2bf(bkv[tid]);
    else if (tid < 384) vext[tid - 192] = f2bf(bkv[tid]);
  }
}

// ---------------- merged Q+KV GEMM: LDS B-panel + fused LN1 prologue ---------
__global__ __launch_bounds__(256, 2) void qkv_gemm(
    const float* __restrict__ x, const float* __restrict__ xa,
    const short* __restrict__ wq_p, const short* __restrict__ wkv_p,
    const float* __restrict__ bq, const float* __restrict__ bkv,
    const float* __restrict__ lg, const float* __restrict__ lb,
    short* __restrict__ qb, short* __restrict__ kb, short* __restrict__ vb) {
  __shared__ __align__(16) short Bls[72 * 512];
  const int y = blockIdx.y;
  const int lane = threadIdx.x & 63;
  const int wv = threadIdx.x >> 6;
  const int lrow = lane & 15, lkg = lane >> 4;
  const int rb = blockIdx.x * 64 + wv * 16;

  const float* Av = (y == 0) ? x : xa;
  const short* Bp = (y == 0) ? wq_p : wkv_p + (size_t)(y - 1) * 72 * 512;

  {
#pragma unroll
    for (int i = 0; i < 18; ++i) {
      int ch = wv * 18 + i;
      __builtin_amdgcn_global_load_lds(
          (const __attribute__((address_space(1))) void*)(Bp + (size_t)ch * 512 + lane * 8),
          (__attribute__((address_space(3))) void*)(Bls + ch * 512), 16, 0, 0);
    }
  }

  bf16x8 af[6];
  {
    const float* Arow = Av + (size_t)(rb + lrow) * 192 + lkg * 8;
    float v[6][8];
    float s = 0.f;
#pragma unroll
    for (int ks = 0; ks < 6; ++ks) {
      float4 lo = *(const float4*)(Arow + ks * 32);
      float4 hi = *(const float4*)(Arow + ks * 32 + 4);
      v[ks][0] = lo.x; v[ks][1] = lo.y; v[ks][2] = lo.z; v[ks][3] = lo.w;
      v[ks][4] = hi.x; v[ks][5] = hi.y; v[ks][6] = hi.z; v[ks][7] = hi.w;
#pragma unroll
      for (int j = 0; j < 8; ++j) s += v[ks][j];
    }
    s += __shfl_xor(s, 16); s += __shfl_xor(s, 32);
    float mean = s * (1.f / 192.f);
    float vs = 0.f;
#pragma unroll
    for (int ks = 0; ks < 6; ++ks)
#pragma unroll
      for (int j = 0; j < 8; ++j) { float d = v[ks][j] - mean; vs += d * d; }
    vs += __shfl_xor(vs, 16); vs += __shfl_xor(vs, 32);
    float rstd = rsqrtf(vs * (1.f / 192.f) + 1e-5f);
#pragma unroll
    for (int ks = 0; ks < 6; ++ks)
#pragma unroll
      for (int j = 0; j < 8; ++j) {
        int ch = ks * 32 + lkg * 8 + j;
        af[ks][j] = f2bf((v[ks][j] - mean) * rstd * lg[ch] + lb[ch]);
      }
  }
  __syncthreads();

  f32x4 acc[12];
#pragma unroll
  for (int c = 0; c < 12; ++c) acc[c] = (f32x4){0.f, 0.f, 0.f, 0.f};
#pragma unroll
  for (int ks = 0; ks < 6; ++ks)
#pragma unroll
    for (int c = 0; c < 12; ++c) {
      bf16x8 bfr = *(const bf16x8*)(Bls + ((c * 6 + ks) * 64 + lane) * 8);
      acc[c] = __builtin_amdgcn_mfma_f32_16x16x32_bf16(af[ks], bfr, acc[c], 0, 0, 0);
    }

  if (y == 0) {
#pragma unroll
    for (int c = 0; c < 12; ++c) {
      int col = c * 16 + lrow;
      float bia = bq[col];
#pragma unroll
      for (int i = 0; i < 4; ++i) {
        int row = rb + lkg * 4 + i;
        qb[(size_t)row * 192 + col] = f2bf((acc[c][i] + bia) * 0.36067376022224085f);
      }
    }
  } else {
    int nb = (y - 1) * 192;
#pragma unroll
    for (int c = 0; c < 12; ++c) {
      int col = nb + c * 16 + lrow;
      float bia = bkv[col];
#pragma unroll
      for (int i = 0; i < 4; ++i) {
        int row = rb + lkg * 4 + i;
        float v = acc[c][i] + bia;
        if (col < 192) kb[(size_t)row * 192 + col] = f2bf(v);
        else           vb[(size_t)row * 192 + col - 192] = f2bf(v);
      }
    }
  }
}

// ---------------- bf16 MFMA GEMM, LDS-staged B-panel, MT row-tiles/wave ------
template <int EPI, int MT, int CT, int K, int NTOT>
__global__ __launch_bounds__(256, 2) void gemm_mfma(const void* __restrict__ Av,
                                                    const short* __restrict__ Bp,
                                                    const float* __restrict__ bias,
                                                    const float* __restrict__ resid,
                                                    const float* __restrict__ lg,
                                                    const float* __restrict__ lb,
                                                    void* __restrict__ C0v,
                                                    void* __restrict__ C1v) {
  constexpr int KS = K / 32;
  constexpr int CHUNKS = CT * KS;  // 1KB each
  static_assert(CHUNKS == 72);
  __shared__ __align__(16) short Bls[CHUNKS * 512];

  const int lane = threadIdx.x & 63;
  const int wv = threadIdx.x >> 6;
  const int lrow = lane & 15, lkg = lane >> 4;
  const int rb = blockIdx.x * (64 * MT) + wv * (16 * MT);
  const int nb = blockIdx.y * (CT * 16);
  const int nb16 = blockIdx.y * CT;

  {
    const short* bsrc = Bp + (size_t)nb16 * KS * 512;
#pragma unroll
    for (int i = 0; i < 18; ++i) {
      int ch = wv * 18 + i;
      __builtin_amdgcn_global_load_lds(
          (const __attribute__((address_space(1))) void*)(bsrc + (size_t)ch * 512 + lane * 8),
          (__attribute__((address_space(3))) void*)(Bls + ch * 512), 16, 0, 0);
    }
  }

  bf16x8 af[MT][KS];
#pragma unroll
  for (int mt = 0; mt < MT; ++mt) {
    const short* Arow = (const short*)Av + (size_t)(rb + mt * 16 + lrow) * K + lkg * 8;
#pragma unroll
    for (int ks = 0; ks < KS; ++ks) af[mt][ks] = *(const bf16x8*)(Arow + ks * 32);
  }
  __syncthreads();

  f32x4 acc[MT][CT];
#pragma unroll
  for (int mt = 0; mt < MT; ++mt)
#pragma unroll
    for (int c = 0; c < CT; ++c) acc[mt][c] = (f32x4){0.f, 0.f, 0.f, 0.f};
#pragma unroll
  for (int ks = 0; ks < KS; ++ks) {
#pragma unroll
    for (int c = 0; c < CT; ++c) {
      bf16x8 bfr = *(const bf16x8*)(Bls + ((c * KS + ks) * 64 + lane) * 8);
#pragma unroll
      for (int mt = 0; mt < MT; ++mt)
        acc[mt][c] = __builtin_amdgcn_mfma_f32_16x16x32_bf16(af[mt][ks], bfr, acc[mt][c], 0, 0, 0);
    }
  }

  if constexpr (EPI == EP_RESID_LN) {
    static_assert(CT == 12);
#pragma unroll
    for (int mt = 0; mt < MT; ++mt) {
#pragma unroll
      for (int c = 0; c < 12; ++c) {
        int col = c * 16 + lrow;
        float bia = bias[col];
#pragma unroll
        for (int i = 0; i < 4; ++i) {
          int row = rb + mt * 16 + lkg * 4 + i;
          acc[mt][c][i] += bia + resid[(size_t)row * 192 + col];
          ((float*)C0v)[(size_t)row * 192 + col] = acc[mt][c][i];
        }
      }
#pragma unroll
      for (int i = 0; i < 4; ++i) {
        int row = rb + mt * 16 + lkg * 4 + i;
        float s2 = 0.f;
#pragma unroll
        for (int c = 0; c < 12; ++c) s2 += acc[mt][c][i];
        s2 += __shfl_xor(s2, 1); s2 += __shfl_xor(s2, 2);
        s2 += __shfl_xor(s2, 4); s2 += __shfl_xor(s2, 8);
        float mean = s2 * (1.f / 192.f);
        float vs2 = 0.f;
#pragma unroll
        for (int c = 0; c < 12; ++c) { float d = acc[mt][c][i] - mean; vs2 += d * d; }
        vs2 += __shfl_xor(vs2, 1); vs2 += __shfl_xor(vs2, 2);
        vs2 += __shfl_xor(vs2, 4); vs2 += __shfl_xor(vs2, 8);
        float rstd = rsqrtf(vs2 * (1.f / 192.f) + 1e-5f);
#pragma unroll
        for (int c = 0; c < 12; ++c) {
          int col = c * 16 + lrow;
          ((short*)C1v)[(size_t)row * 192 + col] =
              f2bf((acc[mt][c][i] - mean) * rstd * lg[col] + lb[col]);
        }
      }
    }
  } else {
#pragma unroll
    for (int mt = 0; mt < MT; ++mt)
#pragma unroll
      for (int c = 0; c < CT; ++c) {
        int col = nb + c * 16 + lrow;
        float bia = bias[col];
#pragma unroll
        for (int i = 0; i < 4; ++i) {
          int row = rb + mt * 16 + lkg * 4 + i;
          float v = acc[mt][c][i] + bia;
          if constexpr (EPI == EP_RESID) {
            ((float*)C0v)[(size_t)row * NTOT + col] = v + resid[(size_t)row * NTOT + col];
          } else {  // EP_GELU
            float gg = 0.5f * v * (1.f + erff(v * 0.70710678118654752f));
            ((short*)C0v)[(size_t)row * NTOT + col] = f2bf(gg);
          }
        }
      }
  }
}

// ---------------- Attention: persistent blocks, 1 wave per (window, head) ----
// 1792 blocks (7/CU), each loops a contiguous XCD-local chunk of items.
// Per item: QK^T 32x32x16 (7 tiles), exp2 softmax, P b16 stores, 16B V path,
// PV 16x16x32 with tr-read B-frags. Barrier-free (wave-private LDS slices).
__global__ __launch_bounds__(128, 3) void attn_mfma(const short* __restrict__ qbuf,
                                                    const short* __restrict__ kbuf,
                                                    const short* __restrict__ vbuf,
                                                    const int* __restrict__ gIdx,
                                                    short* __restrict__ obuf) {
  __shared__ __align__(16) short VsS[2][224 * 16];
  __shared__ __align__(16) short PsS[2][8 * 232];

  const int tid = threadIdx.x;
  const int wv = tid >> 6;
  const int lane = tid & 63;
  const int lrow = lane & 15, lkg = lane >> 4;
  const int l31 = lane & 31, kg2 = lane >> 5;

  short* Vs = VsS[wv];
  short* Ps = PsS[wv];
  int* PsI = (int*)Ps;  // idx scratch (reused before P writes each item)

  // lane-constant LDS addresses / offsets (hoisted out of item loop)
  unsigned vbadr = (unsigned)(size_t)((__attribute__((address_space(3))) short*)Vs)
                 + (unsigned)(lkg * 256 + (lrow >> 2) * 32 + (lane & 3) * 8);

  // XCD-aware contiguous chunk: block b -> chunk (b&7)*224 + (b>>3)
  const unsigned nchunk = ABLOCKS;  // one chunk per block
  const unsigned chunk = (blockIdx.x & 7u) * (nchunk / 8u) + (blockIdx.x >> 3);
  const unsigned per = (AITEMS + nchunk - 1) / nchunk;  // 14
  unsigned ibeg = chunk * per;
  unsigned iend = ibeg + per;
  if (iend > AITEMS) iend = AITEMS;

  for (unsigned item = ibeg; item < iend; ++item) {
    const int w = (int)(item / 6u);
    const int h = (int)(item % 6u) * 2 + wv;
    const int ww = w & 15, wh = (w >> 4) & 15, wd = w >> 8;
    const int wbase = wd * 2048 + wh * 64 + ww * 2;  // window corner token

    // ---- idx table -> LDS (1 int4 per lane, 56 active), broadcast reads
    if (lane < 56) {
      int4 idx4 = ((const int4*)(gIdx + (size_t)w * 224))[lane];
      ((int4*)PsI)[lane] = idx4;
    }
    // ds in-order per wave: reads below see the writes.

    // ---- Q A-frag (32x32x16): row=l31 (query, <8 real), k=kg2*8+j
    bf16x8 qa = (bf16x8)0;
    if (l31 < 8) {
      int n = l31;
      int tq = wbase + (n >> 2) * 1024 + ((n >> 1) & 1) * 32 + (n & 1);
      qa = *(const bf16x8*)(qbuf + (size_t)tq * 192 + h * 16 + kg2 * 8);
    }

    int ti7[7];
#pragma unroll
    for (int T = 0; T < 7; ++T) ti7[T] = PsI[T * 32 + l31];
    int mv7[7];
#pragma unroll
    for (int k = 0; k < 7; ++k) mv7[k] = PsI[(lane >> 1) + k * 32];

    // ---- K B-frags: col=token=l31+32T, k=kg2*8+j; all 64 lanes active
    const unsigned ko = (unsigned)(h * 32 + kg2 * 16);
    bf16x8 kf[7];
#pragma unroll
    for (int T = 0; T < 7; ++T)
      kf[T] = *(const bf16x8*)((const char*)kbuf + (unsigned)ti7[T] + ko);

    // ---- V gathers (16B: token (lane>>1)+32k, channel half lane&1)
    const unsigned vo = (unsigned)(h * 32 + (lane & 1) * 16);
    bf16x8 vv[7];
#pragma unroll
    for (int k = 0; k < 7; ++k)
      vv[k] = *(const bf16x8*)((const char*)vbuf + (unsigned)mv7[k] + vo);

    // ---- QK^T + inline softmax-partial + P store
    const f32x16 zero16 = (f32x16)0.f;
    float sum[4] = {0.f, 0.f, 0.f, 0.f};
#pragma unroll
    for (int T = 0; T < 7; ++T) {
      f32x16 c = __builtin_amdgcn_mfma_f32_32x32x16_bf16(qa, kf[T], zero16, 0, 0, 0);
#pragma unroll
      for (int r = 0; r < 4; ++r) {  // queries q = r + 4*kg2 in regs 0..3
        float sv = c[r];
        if (T == 6 && l31 >= 24) sv = -1e30f;  // tokens 216..223 -> exp2 = 0
        float p = exp2f(sv);
        sum[r] += p;
        Ps[(r + 4 * kg2) * 232 + T * 32 + l31] = f2bf(p);
      }
    }

    // ---- sum reduce over 32-token lanes; inv per query
    float invq[4];
#pragma unroll
    for (int r = 0; r < 4; ++r) {
      float s = sum[r];
      s += __shfl_xor(s, 1);
      s += __shfl_xor(s, 2);
      s += __shfl_xor(s, 4);
      s += __shfl_xor(s, 8);
      s += __shfl_xor(s, 16);
      float iv = 1.f / s;
      float oth = __shfl_xor(iv, 32);
      invq[r] = (lane & 16) ? oth : iv;  // query n=(lane>>4)*4+r mapping
    }

    // ---- V -> LDS (token-major [224][16]): 7 contiguous b128 writes
#pragma unroll
    for (int k = 0; k < 7; ++k)
      *(bf16x8*)(Vs + ((unsigned)lane + (unsigned)k * 64u) * 8u) = vv[k];
    asm volatile("s_waitcnt lgkmcnt(0)" ::: "memory");
    __builtin_amdgcn_sched_barrier(0);

    // ---- PV (16x16x32): tr-reads + P frags, single wait, 7 MFMA
    bf16x4 t0[7], t1[7];
#pragma unroll
    for (int T = 0; T < 7; ++T) {
      unsigned a = vbadr + (unsigned)(T * 1024);
      asm volatile("ds_read_b64_tr_b16 %0, %1" : "=v"(t0[T]) : "v"(a));
      asm volatile("ds_read_b64_tr_b16 %0, %1 offset:128" : "=v"(t1[T]) : "v"(a));
    }
    bf16x8 pa[7];
#pragma unroll
    for (int T = 0; T < 7; ++T) {
      pa[T] = (bf16x8)0;
      if (lrow < 8) pa[T] = *(const bf16x8*)(Ps + lrow * 232 + T * 32 + lkg * 8);
    }
    asm volatile("s_waitcnt lgkmcnt(0)" ::: "memory");
    __builtin_amdgcn_sched_barrier(0);
    f32x4 o = {0.f, 0.f, 0.f, 0.f};
#pragma unroll
    for (int T = 0; T < 7; ++T) {
      bf16x8 vf = __builtin_shufflevector(t0[T], t1[T], 0, 1, 2, 3, 4, 5, 6, 7);
      o = __builtin_amdgcn_mfma_f32_16x16x32_bf16(pa[T], vf, o, 0, 0, 0);
    }

    // ---- store O (bf16, normalized)
    if (lane < 32) {
#pragma unroll
      for (int r = 0; r < 4; ++r) {
        int n = (lane >> 4) * 4 + r;
        int tq = wbase + (n >> 2) * 1024 + ((n >> 1) & 1) * 32 + (n & 1);
        obuf[(size_t)tq * 192 + h * 16 + lrow] = f2bf(o[r] * invq[r]);
      }
    }
  }
}

extern "C" void kernel_launch(void* const* d_in, const int* in_sizes, int n_in,
                              void* d_out, int out_size, void* d_ws, size_t ws_size,
                              hipStream_t stream) {
  const float* x   = (const float*)d_in[0];
  const float* xa  = (const float*)d_in[1];
  const float* n1g = (const float*)d_in[2];
  const float* n1b = (const float*)d_in[3];
  const float* n2g = (const float*)d_in[4];
  const float* n2b = (const float*)d_in[5];
  const float* Wq  = (const float*)d_in[6];
  const float* bq  = (const float*)d_in[7];
  const float* Wkv = (const float*)d_in[8];
  const float* bkv = (const float*)d_in[9];
  const float* Wp  = (const float*)d_in[10];
  const float* bp  = (const float*)d_in[11];
  const float* W1  = (const float*)d_in[12];
  const float* b1  = (const float*)d_in[13];
  const float* W2  = (const float*)d_in[14];
  const float* b2  = (const float*)d_in[15];

  char* wsb = (char*)d_ws;
  const size_t BB = (size_t)TOK * 192 * 2;  // 12.58 MB bf16 token buffer
  short* attn_o = (short*)(wsb + 0 * BB);
  short* xn2    = (short*)(wsb + 1 * BB);               // LN2 out (bf16)
  short* qb     = (short*)(wsb + 2 * BB);               // Q; later hmlp spans qb..kb
  short* kb     = (short*)(wsb + 3 * BB);               // K + ext row TOK
  short* vb     = (short*)(wsb + 4 * BB + 4096);        // V + ext row TOK
  float* x1     = (float*)(wsb + 5 * BB + 8192);        // f32 [TOK][192] (2*BB)
  char* p = wsb + 7 * BB + 16384;
  int* gIdx = (int*)p;            p += (size_t)NWIN * 224 * 4;
  short* wq_p  = (short*)p;       p += 192 * 192 * 2;
  short* wkv_p = (short*)p;       p += 192 * 384 * 2;
  short* wp_p  = (short*)p;       p += 192 * 192 * 2;
  short* w1_p  = (short*)p;       p += 192 * 384 * 2;
  short* w2_p  = (short*)p;       p += 384 * 192 * 2;

  short* hmlp = qb;  // [TOK][384] bf16 spans qb(BB) + kb region

  prep_kernel<<<144 + NWIN + 1, 256, 0, stream>>>(
      Wq, Wkv, Wp, W1, W2, bkv, wq_p, wkv_p, wp_p, w1_p, w2_p,
      kb + (size_t)TOK * 192, vb + (size_t)TOK * 192, gIdx);

  // merged: Q = (LN1(x)@Wq+bq)*0.25*log2e ; K,V = LN1(xa)@Wkv+bkv
  qkv_gemm<<<dim3(512, 3), 256, 0, stream>>>(
      x, xa, wq_p, wkv_p, bq, bkv, n1g, n1b, qb, kb, vb);

  attn_mfma<<<ABLOCKS, 128, 0, stream>>>(qb, kb, vb, gIdx, attn_o);

  // x1 = x + attn_o@Wp+bp ; xn2 = LN2(x1)   (MT=2: 128 rows/block)
  gemm_mfma<EP_RESID_LN, 2, 12, 192, 192><<<dim3(256, 1), 256, 0, stream>>>(
      attn_o, wp_p, bp, x, n2g, n2b, x1, xn2);

  gemm_mfma<EP_GELU, 2, 12, 192, 384><<<dim3(256, 2), 256, 0, stream>>>(
      xn2, w1_p, b1, nullptr, nullptr, nullptr, hmlp, nullptr);
  gemm_mfma<EP_RESID, 2, 6, 384, 192><<<dim3(256, 2), 256, 0, stream>>>(
      hmlp, w2_p, b2, x1, nullptr, nullptr, (float*)d_out, nullptr);
}

// Round 19
// 188.435 us; speedup vs baseline: 1.2105x; 1.2105x over previous
//
#include <hip/hip_runtime.h>
#include <hip/hip_bf16.h>
#include <math.h>

// CrossTransformerBlock3D: D=H=W=32, DIM=192, HEADS=12, HD=16, WS=2x2x2
// bf16-MFMA everywhere. LN1 fused into merged Q+KV GEMM prologue, LN2 into
// P-GEMM epilogue. Q pre-scaled by 0.25*log2e so attn softmax is exp2(s).
// GEMMs: LDS-staged 72KB B-panel (r11 template; MT=2 on P/MLP).
// Attn: persistent blocks (1792 = 7/CU) with STRIDED item loop -- at step j
// all 224 blocks of an XCD process a contiguous 224-item (~37-window) span,
// restoring r17's L2 temporal locality (r18's chunked loop spread the working
// set over 523 windows -> 8.5x HBM refetch). QK^T 32x32x16, 16B V path.

#define TOK 32768
#define NWIN 4096
#define AITEMS (NWIN * 6)
#define ABLOCKS 1792

typedef float f32x4 __attribute__((ext_vector_type(4)));
typedef float f32x16 __attribute__((ext_vector_type(16)));
typedef short bf16x8 __attribute__((ext_vector_type(8)));
typedef short bf16x4 __attribute__((ext_vector_type(4)));

static __device__ __forceinline__ short f2bf(float x) {
  __hip_bfloat16 h = __float2bfloat16(x);
  return __builtin_bit_cast(short, h);
}

enum { EP_RESID_LN = 2, EP_GELU = 3, EP_RESID = 4 };

// ---------------- fused prep: weight packs + neighborhood idx + bkv cast -----
static __device__ __forceinline__ void pack_one(const float* __restrict__ W,
                                                short* __restrict__ dst,
                                                int K, int N, int blk, int lane) {
  int KS = K / 32;
  int ks = blk % KS, c = blk / KS;
  int col = c * 16 + (lane & 15);
  int krow = ks * 32 + (lane >> 4) * 8;
  bf16x8 v;
#pragma unroll
  for (int j = 0; j < 8; ++j) v[j] = f2bf(W[(size_t)(krow + j) * N + col]);
  *(bf16x8*)(dst + ((size_t)blk * 64 + lane) * 8) = v;
}

__global__ __launch_bounds__(256) void prep_kernel(
    const float* __restrict__ Wq, const float* __restrict__ Wkv,
    const float* __restrict__ Wp, const float* __restrict__ W1,
    const float* __restrict__ W2, const float* __restrict__ bkv,
    short* __restrict__ wq_p, short* __restrict__ wkv_p, short* __restrict__ wp_p,
    short* __restrict__ w1_p, short* __restrict__ w2_p,
    short* __restrict__ kext, short* __restrict__ vext,
    int* __restrict__ gIdx) {
  int bid = blockIdx.x;
  int tid = threadIdx.x;
  if (bid < 144) {  // 4 pack-units per block
    int pb = bid * 4 + (tid >> 6);
    int lane = tid & 63;
    if (pb < 72)        pack_one(Wq,  wq_p,  192, 192, pb,       lane);
    else if (pb < 216)  pack_one(Wkv, wkv_p, 192, 384, pb - 72,  lane);
    else if (pb < 288)  pack_one(Wp,  wp_p,  192, 192, pb - 216, lane);
    else if (pb < 432)  pack_one(W1,  w1_p,  192, 384, pb - 288, lane);
    else                pack_one(W2,  w2_p,  384, 192, pb - 432, lane);
  } else if (bid < 144 + NWIN) {  // neighborhood idx -> BYTE offsets
    int w = bid - 144;
    int m = tid;
    if (m >= 224) return;
    int ww = w & 15, wh = (w >> 4) & 15, wd = w >> 8;
    int t = TOK;  // sentinel row = bkv projection
    if (m < 216) {
      int lw = m & 1;  int t1 = m >> 1;
      int dk = t1 % 3; int t2 = t1 / 3;
      int lh = t2 & 1; int t3 = t2 >> 1;
      int dj = t3 % 3; int t4 = t3 / 3;
      int ld = t4 & 1; int di = t4 >> 1;
      int nwd = wd + di - 1, nwh = wh + dj - 1, nww = ww + dk - 1;
      int slab = di * 9 + dj * 3 + dk;
      if (nwd >= 0 && nwd <= 15 && nwh >= 0 && nwh <= 15 && nww >= 0 && nww <= 15 && slab != 20) {
        t = ((nwd * 2 + ld) * 32 + (nwh * 2 + lh)) * 32 + (nww * 2 + lw);
      }
    }
    gIdx[w * 224 + m] = t * 384;  // byte offset into K/V (192 ch * 2B)
  } else {  // bkv extension rows
    if (tid < 192)      kext[tid] = f2bf(bkv[tid]);
    else if (tid < 384) vext[tid - 192] = f2bf(bkv[tid]);
  }
}

// ---------------- merged Q+KV GEMM: LDS B-panel + fused LN1 prologue ---------
__global__ __launch_bounds__(256, 2) void qkv_gemm(
    const float* __restrict__ x, const float* __restrict__ xa,
    const short* __restrict__ wq_p, const short* __restrict__ wkv_p,
    const float* __restrict__ bq, const float* __restrict__ bkv,
    const float* __restrict__ lg, const float* __restrict__ lb,
    short* __restrict__ qb, short* __restrict__ kb, short* __restrict__ vb) {
  __shared__ __align__(16) short Bls[72 * 512];
  const int y = blockIdx.y;
  const int lane = threadIdx.x & 63;
  const int wv = threadIdx.x >> 6;
  const int lrow = lane & 15, lkg = lane >> 4;
  const int rb = blockIdx.x * 64 + wv * 16;

  const float* Av = (y == 0) ? x : xa;
  const short* Bp = (y == 0) ? wq_p : wkv_p + (size_t)(y - 1) * 72 * 512;

  {
#pragma unroll
    for (int i = 0; i < 18; ++i) {
      int ch = wv * 18 + i;
      __builtin_amdgcn_global_load_lds(
          (const __attribute__((address_space(1))) void*)(Bp + (size_t)ch * 512 + lane * 8),
          (__attribute__((address_space(3))) void*)(Bls + ch * 512), 16, 0, 0);
    }
  }

  bf16x8 af[6];
  {
    const float* Arow = Av + (size_t)(rb + lrow) * 192 + lkg * 8;
    float v[6][8];
    float s = 0.f;
#pragma unroll
    for (int ks = 0; ks < 6; ++ks) {
      float4 lo = *(const float4*)(Arow + ks * 32);
      float4 hi = *(const float4*)(Arow + ks * 32 + 4);
      v[ks][0] = lo.x; v[ks][1] = lo.y; v[ks][2] = lo.z; v[ks][3] = lo.w;
      v[ks][4] = hi.x; v[ks][5] = hi.y; v[ks][6] = hi.z; v[ks][7] = hi.w;
#pragma unroll
      for (int j = 0; j < 8; ++j) s += v[ks][j];
    }
    s += __shfl_xor(s, 16); s += __shfl_xor(s, 32);
    float mean = s * (1.f / 192.f);
    float vs = 0.f;
#pragma unroll
    for (int ks = 0; ks < 6; ++ks)
#pragma unroll
      for (int j = 0; j < 8; ++j) { float d = v[ks][j] - mean; vs += d * d; }
    vs += __shfl_xor(vs, 16); vs += __shfl_xor(vs, 32);
    float rstd = rsqrtf(vs * (1.f / 192.f) + 1e-5f);
#pragma unroll
    for (int ks = 0; ks < 6; ++ks)
#pragma unroll
      for (int j = 0; j < 8; ++j) {
        int ch = ks * 32 + lkg * 8 + j;
        af[ks][j] = f2bf((v[ks][j] - mean) * rstd * lg[ch] + lb[ch]);
      }
  }
  __syncthreads();

  f32x4 acc[12];
#pragma unroll
  for (int c = 0; c < 12; ++c) acc[c] = (f32x4){0.f, 0.f, 0.f, 0.f};
#pragma unroll
  for (int ks = 0; ks < 6; ++ks)
#pragma unroll
    for (int c = 0; c < 12; ++c) {
      bf16x8 bfr = *(const bf16x8*)(Bls + ((c * 6 + ks) * 64 + lane) * 8);
      acc[c] = __builtin_amdgcn_mfma_f32_16x16x32_bf16(af[ks], bfr, acc[c], 0, 0, 0);
    }

  if (y == 0) {
#pragma unroll
    for (int c = 0; c < 12; ++c) {
      int col = c * 16 + lrow;
      float bia = bq[col];
#pragma unroll
      for (int i = 0; i < 4; ++i) {
        int row = rb + lkg * 4 + i;
        qb[(size_t)row * 192 + col] = f2bf((acc[c][i] + bia) * 0.36067376022224085f);
      }
    }
  } else {
    int nb = (y - 1) * 192;
#pragma unroll
    for (int c = 0; c < 12; ++c) {
      int col = nb + c * 16 + lrow;
      float bia = bkv[col];
#pragma unroll
      for (int i = 0; i < 4; ++i) {
        int row = rb + lkg * 4 + i;
        float v = acc[c][i] + bia;
        if (col < 192) kb[(size_t)row * 192 + col] = f2bf(v);
        else           vb[(size_t)row * 192 + col - 192] = f2bf(v);
      }
    }
  }
}

// ---------------- bf16 MFMA GEMM, LDS-staged B-panel, MT row-tiles/wave ------
template <int EPI, int MT, int CT, int K, int NTOT>
__global__ __launch_bounds__(256, 2) void gemm_mfma(const void* __restrict__ Av,
                                                    const short* __restrict__ Bp,
                                                    const float* __restrict__ bias,
                                                    const float* __restrict__ resid,
                                                    const float* __restrict__ lg,
                                                    const float* __restrict__ lb,
                                                    void* __restrict__ C0v,
                                                    void* __restrict__ C1v) {
  constexpr int KS = K / 32;
  constexpr int CHUNKS = CT * KS;  // 1KB each
  static_assert(CHUNKS == 72);
  __shared__ __align__(16) short Bls[CHUNKS * 512];

  const int lane = threadIdx.x & 63;
  const int wv = threadIdx.x >> 6;
  const int lrow = lane & 15, lkg = lane >> 4;
  const int rb = blockIdx.x * (64 * MT) + wv * (16 * MT);
  const int nb = blockIdx.y * (CT * 16);
  const int nb16 = blockIdx.y * CT;

  {
    const short* bsrc = Bp + (size_t)nb16 * KS * 512;
#pragma unroll
    for (int i = 0; i < 18; ++i) {
      int ch = wv * 18 + i;
      __builtin_amdgcn_global_load_lds(
          (const __attribute__((address_space(1))) void*)(bsrc + (size_t)ch * 512 + lane * 8),
          (__attribute__((address_space(3))) void*)(Bls + ch * 512), 16, 0, 0);
    }
  }

  bf16x8 af[MT][KS];
#pragma unroll
  for (int mt = 0; mt < MT; ++mt) {
    const short* Arow = (const short*)Av + (size_t)(rb + mt * 16 + lrow) * K + lkg * 8;
#pragma unroll
    for (int ks = 0; ks < KS; ++ks) af[mt][ks] = *(const bf16x8*)(Arow + ks * 32);
  }
  __syncthreads();

  f32x4 acc[MT][CT];
#pragma unroll
  for (int mt = 0; mt < MT; ++mt)
#pragma unroll
    for (int c = 0; c < CT; ++c) acc[mt][c] = (f32x4){0.f, 0.f, 0.f, 0.f};
#pragma unroll
  for (int ks = 0; ks < KS; ++ks) {
#pragma unroll
    for (int c = 0; c < CT; ++c) {
      bf16x8 bfr = *(const bf16x8*)(Bls + ((c * KS + ks) * 64 + lane) * 8);
#pragma unroll
      for (int mt = 0; mt < MT; ++mt)
        acc[mt][c] = __builtin_amdgcn_mfma_f32_16x16x32_bf16(af[mt][ks], bfr, acc[mt][c], 0, 0, 0);
    }
  }

  if constexpr (EPI == EP_RESID_LN) {
    static_assert(CT == 12);
#pragma unroll
    for (int mt = 0; mt < MT; ++mt) {
#pragma unroll
      for (int c = 0; c < 12; ++c) {
        int col = c * 16 + lrow;
        float bia = bias[col];
#pragma unroll
        for (int i = 0; i < 4; ++i) {
          int row = rb + mt * 16 + lkg * 4 + i;
          acc[mt][c][i] += bia + resid[(size_t)row * 192 + col];
          ((float*)C0v)[(size_t)row * 192 + col] = acc[mt][c][i];
        }
      }
#pragma unroll
      for (int i = 0; i < 4; ++i) {
        int row = rb + mt * 16 + lkg * 4 + i;
        float s2 = 0.f;
#pragma unroll
        for (int c = 0; c < 12; ++c) s2 += acc[mt][c][i];
        s2 += __shfl_xor(s2, 1); s2 += __shfl_xor(s2, 2);
        s2 += __shfl_xor(s2, 4); s2 += __shfl_xor(s2, 8);
        float mean = s2 * (1.f / 192.f);
        float vs2 = 0.f;
#pragma unroll
        for (int c = 0; c < 12; ++c) { float d = acc[mt][c][i] - mean; vs2 += d * d; }
        vs2 += __shfl_xor(vs2, 1); vs2 += __shfl_xor(vs2, 2);
        vs2 += __shfl_xor(vs2, 4); vs2 += __shfl_xor(vs2, 8);
        float rstd = rsqrtf(vs2 * (1.f / 192.f) + 1e-5f);
#pragma unroll
        for (int c = 0; c < 12; ++c) {
          int col = c * 16 + lrow;
          ((short*)C1v)[(size_t)row * 192 + col] =
              f2bf((acc[mt][c][i] - mean) * rstd * lg[col] + lb[col]);
        }
      }
    }
  } else {
#pragma unroll
    for (int mt = 0; mt < MT; ++mt)
#pragma unroll
      for (int c = 0; c < CT; ++c) {
        int col = nb + c * 16 + lrow;
        float bia = bias[col];
#pragma unroll
        for (int i = 0; i < 4; ++i) {
          int row = rb + mt * 16 + lkg * 4 + i;
          float v = acc[mt][c][i] + bia;
          if constexpr (EPI == EP_RESID) {
            ((float*)C0v)[(size_t)row * NTOT + col] = v + resid[(size_t)row * NTOT + col];
          } else {  // EP_GELU
            float gg = 0.5f * v * (1.f + erff(v * 0.70710678118654752f));
            ((short*)C0v)[(size_t)row * NTOT + col] = f2bf(gg);
          }
        }
      }
  }
}

// ---------------- Attention: persistent blocks, strided item loop ------------
// 1792 blocks (7/CU). XCD x = bid&7 owns items [x*3072, (x+1)*3072); block
// bl = bid>>3 processes items base+bl, base+bl+224, ... -- all 224 XCD blocks
// cover a contiguous 224-item span at each step (L2-local, r17 semantics).
__global__ __launch_bounds__(128, 3) void attn_mfma(const short* __restrict__ qbuf,
                                                    const short* __restrict__ kbuf,
                                                    const short* __restrict__ vbuf,
                                                    const int* __restrict__ gIdx,
                                                    short* __restrict__ obuf) {
  __shared__ __align__(16) short VsS[2][224 * 16];
  __shared__ __align__(16) short PsS[2][8 * 232];

  const int tid = threadIdx.x;
  const int wv = tid >> 6;
  const int lane = tid & 63;
  const int lrow = lane & 15, lkg = lane >> 4;
  const int l31 = lane & 31, kg2 = lane >> 5;

  short* Vs = VsS[wv];
  short* Ps = PsS[wv];
  int* PsI = (int*)Ps;  // idx scratch (reused before P writes each item)

  unsigned vbadr = (unsigned)(size_t)((__attribute__((address_space(3))) short*)Vs)
                 + (unsigned)(lkg * 256 + (lrow >> 2) * 32 + (lane & 3) * 8);

  const unsigned base = (blockIdx.x & 7u) * 3072u;  // XCD item range
  const unsigned bl = blockIdx.x >> 3;              // 0..223

  for (unsigned off = bl; off < 3072u; off += 224u) {
    const unsigned item = base + off;
    const int w = (int)(item / 6u);
    const int h = (int)(item % 6u) * 2 + wv;
    const int ww = w & 15, wh = (w >> 4) & 15, wd = w >> 8;
    const int wbase = wd * 2048 + wh * 64 + ww * 2;  // window corner token

    // ---- idx table -> LDS (1 int4 per lane, 56 active), broadcast reads
    if (lane < 56) {
      int4 idx4 = ((const int4*)(gIdx + (size_t)w * 224))[lane];
      ((int4*)PsI)[lane] = idx4;
    }
    // ds in-order per wave: reads below see the writes.

    // ---- Q A-frag (32x32x16): row=l31 (query, <8 real), k=kg2*8+j
    bf16x8 qa = (bf16x8)0;
    if (l31 < 8) {
      int n = l31;
      int tq = wbase + (n >> 2) * 1024 + ((n >> 1) & 1) * 32 + (n & 1);
      qa = *(const bf16x8*)(qbuf + (size_t)tq * 192 + h * 16 + kg2 * 8);
    }

    int ti7[7];
#pragma unroll
    for (int T = 0; T < 7; ++T) ti7[T] = PsI[T * 32 + l31];
    int mv7[7];
#pragma unroll
    for (int k = 0; k < 7; ++k) mv7[k] = PsI[(lane >> 1) + k * 32];

    // ---- K B-frags: col=token=l31+32T, k=kg2*8+j; all 64 lanes active
    const unsigned ko = (unsigned)(h * 32 + kg2 * 16);
    bf16x8 kf[7];
#pragma unroll
    for (int T = 0; T < 7; ++T)
      kf[T] = *(const bf16x8*)((const char*)kbuf + (unsigned)ti7[T] + ko);

    // ---- V gathers (16B: token (lane>>1)+32k, channel half lane&1)
    const unsigned vo = (unsigned)(h * 32 + (lane & 1) * 16);
    bf16x8 vv[7];
#pragma unroll
    for (int k = 0; k < 7; ++k)
      vv[k] = *(const bf16x8*)((const char*)vbuf + (unsigned)mv7[k] + vo);

    // ---- QK^T + inline softmax-partial + P store
    const f32x16 zero16 = (f32x16)0.f;
    float sum[4] = {0.f, 0.f, 0.f, 0.f};
#pragma unroll
    for (int T = 0; T < 7; ++T) {
      f32x16 c = __builtin_amdgcn_mfma_f32_32x32x16_bf16(qa, kf[T], zero16, 0, 0, 0);
#pragma unroll
      for (int r = 0; r < 4; ++r) {  // queries q = r + 4*kg2 in regs 0..3
        float sv = c[r];
        if (T == 6 && l31 >= 24) sv = -1e30f;  // tokens 216..223 -> exp2 = 0
        float p = exp2f(sv);
        sum[r] += p;
        Ps[(r + 4 * kg2) * 232 + T * 32 + l31] = f2bf(p);
      }
    }

    // ---- sum reduce over 32-token lanes; inv per query
    float invq[4];
#pragma unroll
    for (int r = 0; r < 4; ++r) {
      float s = sum[r];
      s += __shfl_xor(s, 1);
      s += __shfl_xor(s, 2);
      s += __shfl_xor(s, 4);
      s += __shfl_xor(s, 8);
      s += __shfl_xor(s, 16);
      float iv = 1.f / s;
      float oth = __shfl_xor(iv, 32);
      invq[r] = (lane & 16) ? oth : iv;  // query n=(lane>>4)*4+r mapping
    }

    // ---- V -> LDS (token-major [224][16]): 7 contiguous b128 writes
#pragma unroll
    for (int k = 0; k < 7; ++k)
      *(bf16x8*)(Vs + ((unsigned)lane + (unsigned)k * 64u) * 8u) = vv[k];
    asm volatile("s_waitcnt lgkmcnt(0)" ::: "memory");
    __builtin_amdgcn_sched_barrier(0);

    // ---- PV (16x16x32): tr-reads + P frags, single wait, 7 MFMA
    bf16x4 t0[7], t1[7];
#pragma unroll
    for (int T = 0; T < 7; ++T) {
      unsigned a = vbadr + (unsigned)(T * 1024);
      asm volatile("ds_read_b64_tr_b16 %0, %1" : "=v"(t0[T]) : "v"(a));
      asm volatile("ds_read_b64_tr_b16 %0, %1 offset:128" : "=v"(t1[T]) : "v"(a));
    }
    bf16x8 pa[7];
#pragma unroll
    for (int T = 0; T < 7; ++T) {
      pa[T] = (bf16x8)0;
      if (lrow < 8) pa[T] = *(const bf16x8*)(Ps + lrow * 232 + T * 32 + lkg * 8);
    }
    asm volatile("s_waitcnt lgkmcnt(0)" ::: "memory");
    __builtin_amdgcn_sched_barrier(0);
    f32x4 o = {0.f, 0.f, 0.f, 0.f};
#pragma unroll
    for (int T = 0; T < 7; ++T) {
      bf16x8 vf = __builtin_shufflevector(t0[T], t1[T], 0, 1, 2, 3, 4, 5, 6, 7);
      o = __builtin_amdgcn_mfma_f32_16x16x32_bf16(pa[T], vf, o, 0, 0, 0);
    }

    // ---- store O (bf16, normalized)
    if (lane < 32) {
#pragma unroll
      for (int r = 0; r < 4; ++r) {
        int n = (lane >> 4) * 4 + r;
        int tq = wbase + (n >> 2) * 1024 + ((n >> 1) & 1) * 32 + (n & 1);
        obuf[(size_t)tq * 192 + h * 16 + lrow] = f2bf(o[r] * invq[r]);
      }
    }
  }
}

extern "C" void kernel_launch(void* const* d_in, const int* in_sizes, int n_in,
                              void* d_out, int out_size, void* d_ws, size_t ws_size,
                              hipStream_t stream) {
  const float* x   = (const float*)d_in[0];
  const float* xa  = (const float*)d_in[1];
  const float* n1g = (const float*)d_in[2];
  const float* n1b = (const float*)d_in[3];
  const float* n2g = (const float*)d_in[4];
  const float* n2b = (const float*)d_in[5];
  const float* Wq  = (const float*)d_in[6];
  const float* bq  = (const float*)d_in[7];
  const float* Wkv = (const float*)d_in[8];
  const float* bkv = (const float*)d_in[9];
  const float* Wp  = (const float*)d_in[10];
  const float* bp  = (const float*)d_in[11];
  const float* W1  = (const float*)d_in[12];
  const float* b1  = (const float*)d_in[13];
  const float* W2  = (const float*)d_in[14];
  const float* b2  = (const float*)d_in[15];

  char* wsb = (char*)d_ws;
  const size_t BB = (size_t)TOK * 192 * 2;  // 12.58 MB bf16 token buffer
  short* attn_o = (short*)(wsb + 0 * BB);
  short* xn2    = (short*)(wsb + 1 * BB);               // LN2 out (bf16)
  short* qb     = (short*)(wsb + 2 * BB);               // Q; later hmlp spans qb..kb
  short* kb     = (short*)(wsb + 3 * BB);               // K + ext row TOK
  short* vb     = (short*)(wsb + 4 * BB + 4096);        // V + ext row TOK
  float* x1     = (float*)(wsb + 5 * BB + 8192);        // f32 [TOK][192] (2*BB)
  char* p = wsb + 7 * BB + 16384;
  int* gIdx = (int*)p;            p += (size_t)NWIN * 224 * 4;
  short* wq_p  = (short*)p;       p += 192 * 192 * 2;
  short* wkv_p = (short*)p;       p += 192 * 384 * 2;
  short* wp_p  = (short*)p;       p += 192 * 192 * 2;
  short* w1_p  = (short*)p;       p += 192 * 384 * 2;
  short* w2_p  = (short*)p;       p += 384 * 192 * 2;

  short* hmlp = qb;  // [TOK][384] bf16 spans qb(BB) + kb region

  prep_kernel<<<144 + NWIN + 1, 256, 0, stream>>>(
      Wq, Wkv, Wp, W1, W2, bkv, wq_p, wkv_p, wp_p, w1_p, w2_p,
      kb + (size_t)TOK * 192, vb + (size_t)TOK * 192, gIdx);

  // merged: Q = (LN1(x)@Wq+bq)*0.25*log2e ; K,V = LN1(xa)@Wkv+bkv
  qkv_gemm<<<dim3(512, 3), 256, 0, stream>>>(
      x, xa, wq_p, wkv_p, bq, bkv, n1g, n1b, qb, kb, vb);

  attn_mfma<<<ABLOCKS, 128, 0, stream>>>(qb, kb, vb, gIdx, attn_o);

  // x1 = x + attn_o@Wp+bp ; xn2 = LN2(x1)   (MT=2: 128 rows/block)
  gemm_mfma<EP_RESID_LN, 2, 12, 192, 192><<<dim3(256, 1), 256, 0, stream>>>(
      attn_o, wp_p, bp, x, n2g, n2b, x1, xn2);

  gemm_mfma<EP_GELU, 2, 12, 192, 384><<<dim3(256, 2), 256, 0, stream>>>(
      xn2, w1_p, b1, nullptr, nullptr, nullptr, hmlp, nullptr);
  gemm_mfma<EP_RESID, 2, 6, 384, 192><<<dim3(256, 2), 256, 0, stream>>>(
      hmlp, w2_p, b2, x1, nullptr, nullptr, (float*)d_out, nullptr);
}

// Round 20
// 171.844 us; speedup vs baseline: 1.3274x; 1.0965x over previous
//
#include <hip/hip_runtime.h>
#include <hip/hip_bf16.h>
#include <math.h>

// CrossTransformerBlock3D: D=H=W=32, DIM=192, HEADS=12, HD=16, WS=2x2x2
// bf16-MFMA everywhere. LN1 fused into merged Q+KV GEMM prologue, LN2 into
// P-GEMM epilogue. Q pre-scaled by 0.25*log2e so attn softmax is exp2(s).
// GEMMs: LDS-staged 72KB B-panel (r11 template; MT=2 on P/MLP).
// Attn: r17 config (best measured): 24576 blocks + XCD swizzle, QK^T 32x32x16,
// 16B V path, PV 16x16x32 tr-read. Persistence (r18/r19) regressed: the HW
// dispatcher's consecutive-block concurrency beats hand-built schedules.

#define TOK 32768
#define NWIN 4096

typedef float f32x4 __attribute__((ext_vector_type(4)));
typedef float f32x16 __attribute__((ext_vector_type(16)));
typedef short bf16x8 __attribute__((ext_vector_type(8)));
typedef short bf16x4 __attribute__((ext_vector_type(4)));

static __device__ __forceinline__ short f2bf(float x) {
  __hip_bfloat16 h = __float2bfloat16(x);
  return __builtin_bit_cast(short, h);
}

enum { EP_RESID_LN = 2, EP_GELU = 3, EP_RESID = 4 };

// ---------------- fused prep: weight packs + neighborhood idx + bkv cast -----
static __device__ __forceinline__ void pack_one(const float* __restrict__ W,
                                                short* __restrict__ dst,
                                                int K, int N, int blk, int lane) {
  int KS = K / 32;
  int ks = blk % KS, c = blk / KS;
  int col = c * 16 + (lane & 15);
  int krow = ks * 32 + (lane >> 4) * 8;
  bf16x8 v;
#pragma unroll
  for (int j = 0; j < 8; ++j) v[j] = f2bf(W[(size_t)(krow + j) * N + col]);
  *(bf16x8*)(dst + ((size_t)blk * 64 + lane) * 8) = v;
}

__global__ __launch_bounds__(256) void prep_kernel(
    const float* __restrict__ Wq, const float* __restrict__ Wkv,
    const float* __restrict__ Wp, const float* __restrict__ W1,
    const float* __restrict__ W2, const float* __restrict__ bkv,
    short* __restrict__ wq_p, short* __restrict__ wkv_p, short* __restrict__ wp_p,
    short* __restrict__ w1_p, short* __restrict__ w2_p,
    short* __restrict__ kext, short* __restrict__ vext,
    int* __restrict__ gIdx) {
  int bid = blockIdx.x;
  int tid = threadIdx.x;
  if (bid < 144) {  // 4 pack-units per block
    int pb = bid * 4 + (tid >> 6);
    int lane = tid & 63;
    if (pb < 72)        pack_one(Wq,  wq_p,  192, 192, pb,       lane);
    else if (pb < 216)  pack_one(Wkv, wkv_p, 192, 384, pb - 72,  lane);
    else if (pb < 288)  pack_one(Wp,  wp_p,  192, 192, pb - 216, lane);
    else if (pb < 432)  pack_one(W1,  w1_p,  192, 384, pb - 288, lane);
    else                pack_one(W2,  w2_p,  384, 192, pb - 432, lane);
  } else if (bid < 144 + NWIN) {  // neighborhood idx -> BYTE offsets
    int w = bid - 144;
    int m = tid;
    if (m >= 224) return;
    int ww = w & 15, wh = (w >> 4) & 15, wd = w >> 8;
    int t = TOK;  // sentinel row = bkv projection
    if (m < 216) {
      int lw = m & 1;  int t1 = m >> 1;
      int dk = t1 % 3; int t2 = t1 / 3;
      int lh = t2 & 1; int t3 = t2 >> 1;
      int dj = t3 % 3; int t4 = t3 / 3;
      int ld = t4 & 1; int di = t4 >> 1;
      int nwd = wd + di - 1, nwh = wh + dj - 1, nww = ww + dk - 1;
      int slab = di * 9 + dj * 3 + dk;
      if (nwd >= 0 && nwd <= 15 && nwh >= 0 && nwh <= 15 && nww >= 0 && nww <= 15 && slab != 20) {
        t = ((nwd * 2 + ld) * 32 + (nwh * 2 + lh)) * 32 + (nww * 2 + lw);
      }
    }
    gIdx[w * 224 + m] = t * 384;  // byte offset into K/V (192 ch * 2B)
  } else {  // bkv extension rows
    if (tid < 192)      kext[tid] = f2bf(bkv[tid]);
    else if (tid < 384) vext[tid - 192] = f2bf(bkv[tid]);
  }
}

// ---------------- merged Q+KV GEMM: LDS B-panel + fused LN1 prologue ---------
__global__ __launch_bounds__(256, 2) void qkv_gemm(
    const float* __restrict__ x, const float* __restrict__ xa,
    const short* __restrict__ wq_p, const short* __restrict__ wkv_p,
    const float* __restrict__ bq, const float* __restrict__ bkv,
    const float* __restrict__ lg, const float* __restrict__ lb,
    short* __restrict__ qb, short* __restrict__ kb, short* __restrict__ vb) {
  __shared__ __align__(16) short Bls[72 * 512];
  const int y = blockIdx.y;
  const int lane = threadIdx.x & 63;
  const int wv = threadIdx.x >> 6;
  const int lrow = lane & 15, lkg = lane >> 4;
  const int rb = blockIdx.x * 64 + wv * 16;

  const float* Av = (y == 0) ? x : xa;
  const short* Bp = (y == 0) ? wq_p : wkv_p + (size_t)(y - 1) * 72 * 512;

  {
#pragma unroll
    for (int i = 0; i < 18; ++i) {
      int ch = wv * 18 + i;
      __builtin_amdgcn_global_load_lds(
          (const __attribute__((address_space(1))) void*)(Bp + (size_t)ch * 512 + lane * 8),
          (__attribute__((address_space(3))) void*)(Bls + ch * 512), 16, 0, 0);
    }
  }

  bf16x8 af[6];
  {
    const float* Arow = Av + (size_t)(rb + lrow) * 192 + lkg * 8;
    float v[6][8];
    float s = 0.f;
#pragma unroll
    for (int ks = 0; ks < 6; ++ks) {
      float4 lo = *(const float4*)(Arow + ks * 32);
      float4 hi = *(const float4*)(Arow + ks * 32 + 4);
      v[ks][0] = lo.x; v[ks][1] = lo.y; v[ks][2] = lo.z; v[ks][3] = lo.w;
      v[ks][4] = hi.x; v[ks][5] = hi.y; v[ks][6] = hi.z; v[ks][7] = hi.w;
#pragma unroll
      for (int j = 0; j < 8; ++j) s += v[ks][j];
    }
    s += __shfl_xor(s, 16); s += __shfl_xor(s, 32);
    float mean = s * (1.f / 192.f);
    float vs = 0.f;
#pragma unroll
    for (int ks = 0; ks < 6; ++ks)
#pragma unroll
      for (int j = 0; j < 8; ++j) { float d = v[ks][j] - mean; vs += d * d; }
    vs += __shfl_xor(vs, 16); vs += __shfl_xor(vs, 32);
    float rstd = rsqrtf(vs * (1.f / 192.f) + 1e-5f);
#pragma unroll
    for (int ks = 0; ks < 6; ++ks)
#pragma unroll
      for (int j = 0; j < 8; ++j) {
        int ch = ks * 32 + lkg * 8 + j;
        af[ks][j] = f2bf((v[ks][j] - mean) * rstd * lg[ch] + lb[ch]);
      }
  }
  __syncthreads();

  f32x4 acc[12];
#pragma unroll
  for (int c = 0; c < 12; ++c) acc[c] = (f32x4){0.f, 0.f, 0.f, 0.f};
#pragma unroll
  for (int ks = 0; ks < 6; ++ks)
#pragma unroll
    for (int c = 0; c < 12; ++c) {
      bf16x8 bfr = *(const bf16x8*)(Bls + ((c * 6 + ks) * 64 + lane) * 8);
      acc[c] = __builtin_amdgcn_mfma_f32_16x16x32_bf16(af[ks], bfr, acc[c], 0, 0, 0);
    }

  if (y == 0) {
#pragma unroll
    for (int c = 0; c < 12; ++c) {
      int col = c * 16 + lrow;
      float bia = bq[col];
#pragma unroll
      for (int i = 0; i < 4; ++i) {
        int row = rb + lkg * 4 + i;
        qb[(size_t)row * 192 + col] = f2bf((acc[c][i] + bia) * 0.36067376022224085f);
      }
    }
  } else {
    int nb = (y - 1) * 192;
#pragma unroll
    for (int c = 0; c < 12; ++c) {
      int col = nb + c * 16 + lrow;
      float bia = bkv[col];
#pragma unroll
      for (int i = 0; i < 4; ++i) {
        int row = rb + lkg * 4 + i;
        float v = acc[c][i] + bia;
        if (col < 192) kb[(size_t)row * 192 + col] = f2bf(v);
        else           vb[(size_t)row * 192 + col - 192] = f2bf(v);
      }
    }
  }
}

// ---------------- bf16 MFMA GEMM, LDS-staged B-panel, MT row-tiles/wave ------
template <int EPI, int MT, int CT, int K, int NTOT>
__global__ __launch_bounds__(256, 2) void gemm_mfma(const void* __restrict__ Av,
                                                    const short* __restrict__ Bp,
                                                    const float* __restrict__ bias,
                                                    const float* __restrict__ resid,
                                                    const float* __restrict__ lg,
                                                    const float* __restrict__ lb,
                                                    void* __restrict__ C0v,
                                                    void* __restrict__ C1v) {
  constexpr int KS = K / 32;
  constexpr int CHUNKS = CT * KS;  // 1KB each
  static_assert(CHUNKS == 72);
  __shared__ __align__(16) short Bls[CHUNKS * 512];

  const int lane = threadIdx.x & 63;
  const int wv = threadIdx.x >> 6;
  const int lrow = lane & 15, lkg = lane >> 4;
  const int rb = blockIdx.x * (64 * MT) + wv * (16 * MT);
  const int nb = blockIdx.y * (CT * 16);
  const int nb16 = blockIdx.y * CT;

  {
    const short* bsrc = Bp + (size_t)nb16 * KS * 512;
#pragma unroll
    for (int i = 0; i < 18; ++i) {
      int ch = wv * 18 + i;
      __builtin_amdgcn_global_load_lds(
          (const __attribute__((address_space(1))) void*)(bsrc + (size_t)ch * 512 + lane * 8),
          (__attribute__((address_space(3))) void*)(Bls + ch * 512), 16, 0, 0);
    }
  }

  bf16x8 af[MT][KS];
#pragma unroll
  for (int mt = 0; mt < MT; ++mt) {
    const short* Arow = (const short*)Av + (size_t)(rb + mt * 16 + lrow) * K + lkg * 8;
#pragma unroll
    for (int ks = 0; ks < KS; ++ks) af[mt][ks] = *(const bf16x8*)(Arow + ks * 32);
  }
  __syncthreads();

  f32x4 acc[MT][CT];
#pragma unroll
  for (int mt = 0; mt < MT; ++mt)
#pragma unroll
    for (int c = 0; c < CT; ++c) acc[mt][c] = (f32x4){0.f, 0.f, 0.f, 0.f};
#pragma unroll
  for (int ks = 0; ks < KS; ++ks) {
#pragma unroll
    for (int c = 0; c < CT; ++c) {
      bf16x8 bfr = *(const bf16x8*)(Bls + ((c * KS + ks) * 64 + lane) * 8);
#pragma unroll
      for (int mt = 0; mt < MT; ++mt)
        acc[mt][c] = __builtin_amdgcn_mfma_f32_16x16x32_bf16(af[mt][ks], bfr, acc[mt][c], 0, 0, 0);
    }
  }

  if constexpr (EPI == EP_RESID_LN) {
    static_assert(CT == 12);
#pragma unroll
    for (int mt = 0; mt < MT; ++mt) {
#pragma unroll
      for (int c = 0; c < 12; ++c) {
        int col = c * 16 + lrow;
        float bia = bias[col];
#pragma unroll
        for (int i = 0; i < 4; ++i) {
          int row = rb + mt * 16 + lkg * 4 + i;
          acc[mt][c][i] += bia + resid[(size_t)row * 192 + col];
          ((float*)C0v)[(size_t)row * 192 + col] = acc[mt][c][i];
        }
      }
#pragma unroll
      for (int i = 0; i < 4; ++i) {
        int row = rb + mt * 16 + lkg * 4 + i;
        float s2 = 0.f;
#pragma unroll
        for (int c = 0; c < 12; ++c) s2 += acc[mt][c][i];
        s2 += __shfl_xor(s2, 1); s2 += __shfl_xor(s2, 2);
        s2 += __shfl_xor(s2, 4); s2 += __shfl_xor(s2, 8);
        float mean = s2 * (1.f / 192.f);
        float vs2 = 0.f;
#pragma unroll
        for (int c = 0; c < 12; ++c) { float d = acc[mt][c][i] - mean; vs2 += d * d; }
        vs2 += __shfl_xor(vs2, 1); vs2 += __shfl_xor(vs2, 2);
        vs2 += __shfl_xor(vs2, 4); vs2 += __shfl_xor(vs2, 8);
        float rstd = rsqrtf(vs2 * (1.f / 192.f) + 1e-5f);
#pragma unroll
        for (int c = 0; c < 12; ++c) {
          int col = c * 16 + lrow;
          ((short*)C1v)[(size_t)row * 192 + col] =
              f2bf((acc[mt][c][i] - mean) * rstd * lg[col] + lb[col]);
        }
      }
    }
  } else {
#pragma unroll
    for (int mt = 0; mt < MT; ++mt)
#pragma unroll
      for (int c = 0; c < CT; ++c) {
        int col = nb + c * 16 + lrow;
        float bia = bias[col];
#pragma unroll
        for (int i = 0; i < 4; ++i) {
          int row = rb + mt * 16 + lkg * 4 + i;
          float v = acc[mt][c][i] + bia;
          if constexpr (EPI == EP_RESID) {
            ((float*)C0v)[(size_t)row * NTOT + col] = v + resid[(size_t)row * NTOT + col];
          } else {  // EP_GELU
            float gg = 0.5f * v * (1.f + erff(v * 0.70710678118654752f));
            ((short*)C0v)[(size_t)row * NTOT + col] = f2bf(gg);
          }
        }
      }
  }
}

// ---------------- Attention: 1 wave per (window, head), barrier-free ---------
// QK^T 32x32x16 (7 tiles, all 64 lanes real). V path 16B-wide: 7 gathers,
// 7 contiguous b128 LDS writes, 7 idx reads. PV 16x16x32 with tr-read B-frags.
__global__ __launch_bounds__(128, 3) void attn_mfma(const short* __restrict__ qbuf,
                                                    const short* __restrict__ kbuf,
                                                    const short* __restrict__ vbuf,
                                                    const int* __restrict__ gIdx,
                                                    short* __restrict__ obuf) {
  __shared__ __align__(16) short VsS[2][224 * 16];
  __shared__ __align__(16) short PsS[2][8 * 232];

  const int tid = threadIdx.x;
  const int wv = tid >> 6;
  const int lane = tid & 63;
  const int lrow = lane & 15, lkg = lane >> 4;
  const int l31 = lane & 31, kg2 = lane >> 5;

  unsigned bid = blockIdx.x;
  unsigned u = (bid & 7u) * 3072u + (bid >> 3);  // bijective, 24576 blocks
  int w = (int)(u / 6u);
  int h = (int)(u % 6u) * 2 + wv;
  const int ww = w & 15, wh = (w >> 4) & 15, wd = w >> 8;
  const int wbase = wd * 2048 + wh * 64 + ww * 2;  // token of window corner

  short* Vs = VsS[wv];
  short* Ps = PsS[wv];

  // ---- idx table -> LDS (1 int4 per lane, 56 active), broadcast reads
  int* PsI = (int*)Ps;  // scratch before P writes
  if (lane < 56) {
    int4 idx4 = ((const int4*)(gIdx + (size_t)w * 224))[lane];
    ((int4*)PsI)[lane] = idx4;
  }
  // ds in-order per wave: reads below see the writes.

  // ---- Q A-frag (32x32x16): row=l31 (query, <8 real), k=kg2*8+j
  bf16x8 qa = (bf16x8)0;
  if (l31 < 8) {
    int n = l31;
    int tq = wbase + (n >> 2) * 1024 + ((n >> 1) & 1) * 32 + (n & 1);
    qa = *(const bf16x8*)(qbuf + (size_t)tq * 192 + h * 16 + kg2 * 8);
  }

  int ti7[7];
#pragma unroll
  for (int T = 0; T < 7; ++T) ti7[T] = PsI[T * 32 + l31];
  int mv7[7];
#pragma unroll
  for (int k = 0; k < 7; ++k) mv7[k] = PsI[(lane >> 1) + k * 32];

  // ---- K B-frags (32x32x16): col=token=l31+32T, k=kg2*8+j; all lanes active
  const unsigned ko = (unsigned)(h * 32 + kg2 * 16);
  bf16x8 kf[7];
#pragma unroll
  for (int T = 0; T < 7; ++T)
    kf[T] = *(const bf16x8*)((const char*)kbuf + (unsigned)ti7[T] + ko);

  // ---- V gathers (16B each: token (lane>>1)+32k, channel half lane&1)
  const unsigned vo = (unsigned)(h * 32 + (lane & 1) * 16);
  bf16x8 vv[7];
#pragma unroll
  for (int k = 0; k < 7; ++k)
    vv[k] = *(const bf16x8*)((const char*)vbuf + (unsigned)mv7[k] + vo);

  // ---- QK^T + inline softmax-partial + P store (per tile; one C live)
  const f32x16 zero16 = (f32x16)0.f;
  float sum[4] = {0.f, 0.f, 0.f, 0.f};
#pragma unroll
  for (int T = 0; T < 7; ++T) {
    f32x16 c = __builtin_amdgcn_mfma_f32_32x32x16_bf16(qa, kf[T], zero16, 0, 0, 0);
#pragma unroll
    for (int r = 0; r < 4; ++r) {  // queries q = r + 4*kg2 in regs 0..3
      float sv = c[r];
      if (T == 6 && l31 >= 24) sv = -1e30f;  // tokens 216..223 -> exp2 = 0
      float p = exp2f(sv);
      sum[r] += p;
      Ps[(r + 4 * kg2) * 232 + T * 32 + l31] = f2bf(p);
    }
  }

  // ---- sum reduce over 32-token lanes; inv per query
  float invq[4];
#pragma unroll
  for (int r = 0; r < 4; ++r) {
    float s = sum[r];
    s += __shfl_xor(s, 1);
    s += __shfl_xor(s, 2);
    s += __shfl_xor(s, 4);
    s += __shfl_xor(s, 8);
    s += __shfl_xor(s, 16);
    float iv = 1.f / s;
    float oth = __shfl_xor(iv, 32);
    invq[r] = (lane & 16) ? oth : iv;  // query n=(lane>>4)*4+r mapping
  }

  // ---- V -> LDS (token-major [224][16]): 7 contiguous b128 writes
#pragma unroll
  for (int k = 0; k < 7; ++k)
    *(bf16x8*)(Vs + ((unsigned)lane + (unsigned)k * 64u) * 8u) = vv[k];
  asm volatile("s_waitcnt lgkmcnt(0)" ::: "memory");
  __builtin_amdgcn_sched_barrier(0);

  // ---- PV (16x16x32): tr-reads + P frags, single wait, 7 MFMA
  unsigned vbadr = (unsigned)(size_t)((__attribute__((address_space(3))) short*)Vs)
                 + (unsigned)(lkg * 256 + (lrow >> 2) * 32 + (lane & 3) * 8);
  bf16x4 t0[7], t1[7];
#pragma unroll
  for (int T = 0; T < 7; ++T) {
    unsigned a = vbadr + (unsigned)(T * 1024);
    asm volatile("ds_read_b64_tr_b16 %0, %1" : "=v"(t0[T]) : "v"(a));
    asm volatile("ds_read_b64_tr_b16 %0, %1 offset:128" : "=v"(t1[T]) : "v"(a));
  }
  bf16x8 pa[7];
#pragma unroll
  for (int T = 0; T < 7; ++T) {
    pa[T] = (bf16x8)0;
    if (lrow < 8) pa[T] = *(const bf16x8*)(Ps + lrow * 232 + T * 32 + lkg * 8);
  }
  asm volatile("s_waitcnt lgkmcnt(0)" ::: "memory");
  __builtin_amdgcn_sched_barrier(0);
  f32x4 o = {0.f, 0.f, 0.f, 0.f};
#pragma unroll
  for (int T = 0; T < 7; ++T) {
    bf16x8 vf = __builtin_shufflevector(t0[T], t1[T], 0, 1, 2, 3, 4, 5, 6, 7);
    o = __builtin_amdgcn_mfma_f32_16x16x32_bf16(pa[T], vf, o, 0, 0, 0);
  }

  // ---- store O (bf16, normalized)
  if (lane < 32) {
#pragma unroll
    for (int r = 0; r < 4; ++r) {
      int n = (lane >> 4) * 4 + r;
      int tq = wbase + (n >> 2) * 1024 + ((n >> 1) & 1) * 32 + (n & 1);
      obuf[(size_t)tq * 192 + h * 16 + lrow] = f2bf(o[r] * invq[r]);
    }
  }
}

extern "C" void kernel_launch(void* const* d_in, const int* in_sizes, int n_in,
                              void* d_out, int out_size, void* d_ws, size_t ws_size,
                              hipStream_t stream) {
  const float* x   = (const float*)d_in[0];
  const float* xa  = (const float*)d_in[1];
  const float* n1g = (const float*)d_in[2];
  const float* n1b = (const float*)d_in[3];
  const float* n2g = (const float*)d_in[4];
  const float* n2b = (const float*)d_in[5];
  const float* Wq  = (const float*)d_in[6];
  const float* bq  = (const float*)d_in[7];
  const float* Wkv = (const float*)d_in[8];
  const float* bkv = (const float*)d_in[9];
  const float* Wp  = (const float*)d_in[10];
  const float* bp  = (const float*)d_in[11];
  const float* W1  = (const float*)d_in[12];
  const float* b1  = (const float*)d_in[13];
  const float* W2  = (const float*)d_in[14];
  const float* b2  = (const float*)d_in[15];

  char* wsb = (char*)d_ws;
  const size_t BB = (size_t)TOK * 192 * 2;  // 12.58 MB bf16 token buffer
  short* attn_o = (short*)(wsb + 0 * BB);
  short* xn2    = (short*)(wsb + 1 * BB);               // LN2 out (bf16)
  short* qb     = (short*)(wsb + 2 * BB);               // Q; later hmlp spans qb..kb
  short* kb     = (short*)(wsb + 3 * BB);               // K + ext row TOK
  short* vb     = (short*)(wsb + 4 * BB + 4096);        // V + ext row TOK
  float* x1     = (float*)(wsb + 5 * BB + 8192);        // f32 [TOK][192] (2*BB)
  char* p = wsb + 7 * BB + 16384;
  int* gIdx = (int*)p;            p += (size_t)NWIN * 224 * 4;
  short* wq_p  = (short*)p;       p += 192 * 192 * 2;
  short* wkv_p = (short*)p;       p += 192 * 384 * 2;
  short* wp_p  = (short*)p;       p += 192 * 192 * 2;
  short* w1_p  = (short*)p;       p += 192 * 384 * 2;
  short* w2_p  = (short*)p;       p += 384 * 192 * 2;

  short* hmlp = qb;  // [TOK][384] bf16 spans qb(BB) + kb region

  prep_kernel<<<144 + NWIN + 1, 256, 0, stream>>>(
      Wq, Wkv, Wp, W1, W2, bkv, wq_p, wkv_p, wp_p, w1_p, w2_p,
      kb + (size_t)TOK * 192, vb + (size_t)TOK * 192, gIdx);

  // merged: Q = (LN1(x)@Wq+bq)*0.25*log2e ; K,V = LN1(xa)@Wkv+bkv
  qkv_gemm<<<dim3(512, 3), 256, 0, stream>>>(
      x, xa, wq_p, wkv_p, bq, bkv, n1g, n1b, qb, kb, vb);

  attn_mfma<<<NWIN * 6, 128, 0, stream>>>(qb, kb, vb, gIdx, attn_o);

  // x1 = x + attn_o@Wp+bp ; xn2 = LN2(x1)   (MT=2: 128 rows/block)
  gemm_mfma<EP_RESID_LN, 2, 12, 192, 192><<<dim3(256, 1), 256, 0, stream>>>(
      attn_o, wp_p, bp, x, n2g, n2b, x1, xn2);

  gemm_mfma<EP_GELU, 2, 12, 192, 384><<<dim3(256, 2), 256, 0, stream>>>(
      xn2, w1_p, b1, nullptr, nullptr, nullptr, hmlp, nullptr);
  gemm_mfma<EP_RESID, 2, 6, 384, 192><<<dim3(256, 2), 256, 0, stream>>>(
      hmlp, w2_p, b2, x1, nullptr, nullptr, (float*)d_out, nullptr);
}

// Round 21
// 170.895 us; speedup vs baseline: 1.3348x; 1.0056x over previous
//
#include <hip/hip_runtime.h>
#include <hip/hip_bf16.h>
#include <math.h>

// CrossTransformerBlock3D: D=H=W=32, DIM=192, HEADS=12, HD=16, WS=2x2x2
// bf16-MFMA everywhere. LN1 fused into merged Q+KV GEMM prologue, LN2 into
// P-GEMM epilogue. Q pre-scaled by 0.25*log2e so attn softmax is exp2(s).
// GEMMs: LDS-staged 72KB B-panel (r11 template; MT=2 on P/MLP).
// Attn: 2 heads per wave (same window), software-pipelined: item B's K/V
// gathers issue during item A's PV phase -- gather latency paid once per two
// items; idx table read once. LDS reused sequentially (DS ops wave-ordered).

#define TOK 32768
#define NWIN 4096

typedef float f32x4 __attribute__((ext_vector_type(4)));
typedef float f32x16 __attribute__((ext_vector_type(16)));
typedef short bf16x8 __attribute__((ext_vector_type(8)));
typedef short bf16x4 __attribute__((ext_vector_type(4)));

static __device__ __forceinline__ short f2bf(float x) {
  __hip_bfloat16 h = __float2bfloat16(x);
  return __builtin_bit_cast(short, h);
}

enum { EP_RESID_LN = 2, EP_GELU = 3, EP_RESID = 4 };

// ---------------- fused prep: weight packs + neighborhood idx + bkv cast -----
static __device__ __forceinline__ void pack_one(const float* __restrict__ W,
                                                short* __restrict__ dst,
                                                int K, int N, int blk, int lane) {
  int KS = K / 32;
  int ks = blk % KS, c = blk / KS;
  int col = c * 16 + (lane & 15);
  int krow = ks * 32 + (lane >> 4) * 8;
  bf16x8 v;
#pragma unroll
  for (int j = 0; j < 8; ++j) v[j] = f2bf(W[(size_t)(krow + j) * N + col]);
  *(bf16x8*)(dst + ((size_t)blk * 64 + lane) * 8) = v;
}

__global__ __launch_bounds__(256) void prep_kernel(
    const float* __restrict__ Wq, const float* __restrict__ Wkv,
    const float* __restrict__ Wp, const float* __restrict__ W1,
    const float* __restrict__ W2, const float* __restrict__ bkv,
    short* __restrict__ wq_p, short* __restrict__ wkv_p, short* __restrict__ wp_p,
    short* __restrict__ w1_p, short* __restrict__ w2_p,
    short* __restrict__ kext, short* __restrict__ vext,
    int* __restrict__ gIdx) {
  int bid = blockIdx.x;
  int tid = threadIdx.x;
  if (bid < 144) {  // 4 pack-units per block
    int pb = bid * 4 + (tid >> 6);
    int lane = tid & 63;
    if (pb < 72)        pack_one(Wq,  wq_p,  192, 192, pb,       lane);
    else if (pb < 216)  pack_one(Wkv, wkv_p, 192, 384, pb - 72,  lane);
    else if (pb < 288)  pack_one(Wp,  wp_p,  192, 192, pb - 216, lane);
    else if (pb < 432)  pack_one(W1,  w1_p,  192, 384, pb - 288, lane);
    else                pack_one(W2,  w2_p,  384, 192, pb - 432, lane);
  } else if (bid < 144 + NWIN) {  // neighborhood idx -> BYTE offsets
    int w = bid - 144;
    int m = tid;
    if (m >= 224) return;
    int ww = w & 15, wh = (w >> 4) & 15, wd = w >> 8;
    int t = TOK;  // sentinel row = bkv projection
    if (m < 216) {
      int lw = m & 1;  int t1 = m >> 1;
      int dk = t1 % 3; int t2 = t1 / 3;
      int lh = t2 & 1; int t3 = t2 >> 1;
      int dj = t3 % 3; int t4 = t3 / 3;
      int ld = t4 & 1; int di = t4 >> 1;
      int nwd = wd + di - 1, nwh = wh + dj - 1, nww = ww + dk - 1;
      int slab = di * 9 + dj * 3 + dk;
      if (nwd >= 0 && nwd <= 15 && nwh >= 0 && nwh <= 15 && nww >= 0 && nww <= 15 && slab != 20) {
        t = ((nwd * 2 + ld) * 32 + (nwh * 2 + lh)) * 32 + (nww * 2 + lw);
      }
    }
    gIdx[w * 224 + m] = t * 384;  // byte offset into K/V (192 ch * 2B)
  } else {  // bkv extension rows
    if (tid < 192)      kext[tid] = f2bf(bkv[tid]);
    else if (tid < 384) vext[tid - 192] = f2bf(bkv[tid]);
  }
}

// ---------------- merged Q+KV GEMM: LDS B-panel + fused LN1 prologue ---------
__global__ __launch_bounds__(256, 2) void qkv_gemm(
    const float* __restrict__ x, const float* __restrict__ xa,
    const short* __restrict__ wq_p, const short* __restrict__ wkv_p,
    const float* __restrict__ bq, const float* __restrict__ bkv,
    const float* __restrict__ lg, const float* __restrict__ lb,
    short* __restrict__ qb, short* __restrict__ kb, short* __restrict__ vb) {
  __shared__ __align__(16) short Bls[72 * 512];
  const int y = blockIdx.y;
  const int lane = threadIdx.x & 63;
  const int wv = threadIdx.x >> 6;
  const int lrow = lane & 15, lkg = lane >> 4;
  const int rb = blockIdx.x * 64 + wv * 16;

  const float* Av = (y == 0) ? x : xa;
  const short* Bp = (y == 0) ? wq_p : wkv_p + (size_t)(y - 1) * 72 * 512;

  {
#pragma unroll
    for (int i = 0; i < 18; ++i) {
      int ch = wv * 18 + i;
      __builtin_amdgcn_global_load_lds(
          (const __attribute__((address_space(1))) void*)(Bp + (size_t)ch * 512 + lane * 8),
          (__attribute__((address_space(3))) void*)(Bls + ch * 512), 16, 0, 0);
    }
  }

  bf16x8 af[6];
  {
    const float* Arow = Av + (size_t)(rb + lrow) * 192 + lkg * 8;
    float v[6][8];
    float s = 0.f;
#pragma unroll
    for (int ks = 0; ks < 6; ++ks) {
      float4 lo = *(const float4*)(Arow + ks * 32);
      float4 hi = *(const float4*)(Arow + ks * 32 + 4);
      v[ks][0] = lo.x; v[ks][1] = lo.y; v[ks][2] = lo.z; v[ks][3] = lo.w;
      v[ks][4] = hi.x; v[ks][5] = hi.y; v[ks][6] = hi.z; v[ks][7] = hi.w;
#pragma unroll
      for (int j = 0; j < 8; ++j) s += v[ks][j];
    }
    s += __shfl_xor(s, 16); s += __shfl_xor(s, 32);
    float mean = s * (1.f / 192.f);
    float vs = 0.f;
#pragma unroll
    for (int ks = 0; ks < 6; ++ks)
#pragma unroll
      for (int j = 0; j < 8; ++j) { float d = v[ks][j] - mean; vs += d * d; }
    vs += __shfl_xor(vs, 16); vs += __shfl_xor(vs, 32);
    float rstd = rsqrtf(vs * (1.f / 192.f) + 1e-5f);
#pragma unroll
    for (int ks = 0; ks < 6; ++ks)
#pragma unroll
      for (int j = 0; j < 8; ++j) {
        int ch = ks * 32 + lkg * 8 + j;
        af[ks][j] = f2bf((v[ks][j] - mean) * rstd * lg[ch] + lb[ch]);
      }
  }
  __syncthreads();

  f32x4 acc[12];
#pragma unroll
  for (int c = 0; c < 12; ++c) acc[c] = (f32x4){0.f, 0.f, 0.f, 0.f};
#pragma unroll
  for (int ks = 0; ks < 6; ++ks)
#pragma unroll
    for (int c = 0; c < 12; ++c) {
      bf16x8 bfr = *(const bf16x8*)(Bls + ((c * 6 + ks) * 64 + lane) * 8);
      acc[c] = __builtin_amdgcn_mfma_f32_16x16x32_bf16(af[ks], bfr, acc[c], 0, 0, 0);
    }

  if (y == 0) {
#pragma unroll
    for (int c = 0; c < 12; ++c) {
      int col = c * 16 + lrow;
      float bia = bq[col];
#pragma unroll
      for (int i = 0; i < 4; ++i) {
        int row = rb + lkg * 4 + i;
        qb[(size_t)row * 192 + col] = f2bf((acc[c][i] + bia) * 0.36067376022224085f);
      }
    }
  } else {
    int nb = (y - 1) * 192;
#pragma unroll
    for (int c = 0; c < 12; ++c) {
      int col = nb + c * 16 + lrow;
      float bia = bkv[col];
#pragma unroll
      for (int i = 0; i < 4; ++i) {
        int row = rb + lkg * 4 + i;
        float v = acc[c][i] + bia;
        if (col < 192) kb[(size_t)row * 192 + col] = f2bf(v);
        else           vb[(size_t)row * 192 + col - 192] = f2bf(v);
      }
    }
  }
}

// ---------------- bf16 MFMA GEMM, LDS-staged B-panel, MT row-tiles/wave ------
template <int EPI, int MT, int CT, int K, int NTOT>
__global__ __launch_bounds__(256, 2) void gemm_mfma(const void* __restrict__ Av,
                                                    const short* __restrict__ Bp,
                                                    const float* __restrict__ bias,
                                                    const float* __restrict__ resid,
                                                    const float* __restrict__ lg,
                                                    const float* __restrict__ lb,
                                                    void* __restrict__ C0v,
                                                    void* __restrict__ C1v) {
  constexpr int KS = K / 32;
  constexpr int CHUNKS = CT * KS;  // 1KB each
  static_assert(CHUNKS == 72);
  __shared__ __align__(16) short Bls[CHUNKS * 512];

  const int lane = threadIdx.x & 63;
  const int wv = threadIdx.x >> 6;
  const int lrow = lane & 15, lkg = lane >> 4;
  const int rb = blockIdx.x * (64 * MT) + wv * (16 * MT);
  const int nb = blockIdx.y * (CT * 16);
  const int nb16 = blockIdx.y * CT;

  {
    const short* bsrc = Bp + (size_t)nb16 * KS * 512;
#pragma unroll
    for (int i = 0; i < 18; ++i) {
      int ch = wv * 18 + i;
      __builtin_amdgcn_global_load_lds(
          (const __attribute__((address_space(1))) void*)(bsrc + (size_t)ch * 512 + lane * 8),
          (__attribute__((address_space(3))) void*)(Bls + ch * 512), 16, 0, 0);
    }
  }

  bf16x8 af[MT][KS];
#pragma unroll
  for (int mt = 0; mt < MT; ++mt) {
    const short* Arow = (const short*)Av + (size_t)(rb + mt * 16 + lrow) * K + lkg * 8;
#pragma unroll
    for (int ks = 0; ks < KS; ++ks) af[mt][ks] = *(const bf16x8*)(Arow + ks * 32);
  }
  __syncthreads();

  f32x4 acc[MT][CT];
#pragma unroll
  for (int mt = 0; mt < MT; ++mt)
#pragma unroll
    for (int c = 0; c < CT; ++c) acc[mt][c] = (f32x4){0.f, 0.f, 0.f, 0.f};
#pragma unroll
  for (int ks = 0; ks < KS; ++ks) {
#pragma unroll
    for (int c = 0; c < CT; ++c) {
      bf16x8 bfr = *(const bf16x8*)(Bls + ((c * KS + ks) * 64 + lane) * 8);
#pragma unroll
      for (int mt = 0; mt < MT; ++mt)
        acc[mt][c] = __builtin_amdgcn_mfma_f32_16x16x32_bf16(af[mt][ks], bfr, acc[mt][c], 0, 0, 0);
    }
  }

  if constexpr (EPI == EP_RESID_LN) {
    static_assert(CT == 12);
#pragma unroll
    for (int mt = 0; mt < MT; ++mt) {
#pragma unroll
      for (int c = 0; c < 12; ++c) {
        int col = c * 16 + lrow;
        float bia = bias[col];
#pragma unroll
        for (int i = 0; i < 4; ++i) {
          int row = rb + mt * 16 + lkg * 4 + i;
          acc[mt][c][i] += bia + resid[(size_t)row * 192 + col];
          ((float*)C0v)[(size_t)row * 192 + col] = acc[mt][c][i];
        }
      }
#pragma unroll
      for (int i = 0; i < 4; ++i) {
        int row = rb + mt * 16 + lkg * 4 + i;
        float s2 = 0.f;
#pragma unroll
        for (int c = 0; c < 12; ++c) s2 += acc[mt][c][i];
        s2 += __shfl_xor(s2, 1); s2 += __shfl_xor(s2, 2);
        s2 += __shfl_xor(s2, 4); s2 += __shfl_xor(s2, 8);
        float mean = s2 * (1.f / 192.f);
        float vs2 = 0.f;
#pragma unroll
        for (int c = 0; c < 12; ++c) { float d = acc[mt][c][i] - mean; vs2 += d * d; }
        vs2 += __shfl_xor(vs2, 1); vs2 += __shfl_xor(vs2, 2);
        vs2 += __shfl_xor(vs2, 4); vs2 += __shfl_xor(vs2, 8);
        float rstd = rsqrtf(vs2 * (1.f / 192.f) + 1e-5f);
#pragma unroll
        for (int c = 0; c < 12; ++c) {
          int col = c * 16 + lrow;
          ((short*)C1v)[(size_t)row * 192 + col] =
              f2bf((acc[mt][c][i] - mean) * rstd * lg[col] + lb[col]);
        }
      }
    }
  } else {
#pragma unroll
    for (int mt = 0; mt < MT; ++mt)
#pragma unroll
      for (int c = 0; c < CT; ++c) {
        int col = nb + c * 16 + lrow;
        float bia = bias[col];
#pragma unroll
        for (int i = 0; i < 4; ++i) {
          int row = rb + mt * 16 + lkg * 4 + i;
          float v = acc[mt][c][i] + bia;
          if constexpr (EPI == EP_RESID) {
            ((float*)C0v)[(size_t)row * NTOT + col] = v + resid[(size_t)row * NTOT + col];
          } else {  // EP_GELU
            float gg = 0.5f * v * (1.f + erff(v * 0.70710678118654752f));
            ((short*)C0v)[(size_t)row * NTOT + col] = f2bf(gg);
          }
        }
      }
  }
}

// ---------------- Attention: 2 heads/wave, software-pipelined ----------------
// 12288 blocks (NWIN*3, XCD swizzle). Wave wv of block (w, qd) processes
// heads hA=4qd+wv and hB=hA+2 of window w. Indices read ONCE (same window).
// Item B's K/V gathers issue after A's softmax -> latency hides under A's PV.
// LDS (Ps/Vs) reused sequentially; DS ops are wave-ordered so no hazard.
__global__ __launch_bounds__(128, 3) void attn_mfma(const short* __restrict__ qbuf,
                                                    const short* __restrict__ kbuf,
                                                    const short* __restrict__ vbuf,
                                                    const int* __restrict__ gIdx,
                                                    short* __restrict__ obuf) {
  __shared__ __align__(16) short VsS[2][224 * 16];
  __shared__ __align__(16) short PsS[2][8 * 232];

  const int tid = threadIdx.x;
  const int wv = tid >> 6;
  const int lane = tid & 63;
  const int lrow = lane & 15, lkg = lane >> 4;
  const int l31 = lane & 31, kg2 = lane >> 5;

  unsigned bid = blockIdx.x;
  unsigned u = (bid & 7u) * 1536u + (bid >> 3);  // bijective, 12288 blocks
  int w = (int)(u / 3u);
  int qd = (int)(u % 3u);
  const int hA = qd * 4 + wv;
  const int hB = hA + 2;
  const int ww = w & 15, wh = (w >> 4) & 15, wd = w >> 8;
  const int wbase = wd * 2048 + wh * 64 + ww * 2;  // token of window corner

  short* Vs = VsS[wv];
  short* Ps = PsS[wv];

  // ---- idx table -> LDS once (1 int4 per lane, 56 active), broadcast reads
  int* PsI = (int*)Ps;  // scratch before P writes
  if (lane < 56) {
    int4 idx4 = ((const int4*)(gIdx + (size_t)w * 224))[lane];
    ((int4*)PsI)[lane] = idx4;
  }
  int ti7[7];
#pragma unroll
  for (int T = 0; T < 7; ++T) ti7[T] = PsI[T * 32 + l31];
  int mv7[7];
#pragma unroll
  for (int k = 0; k < 7; ++k) mv7[k] = PsI[(lane >> 1) + k * 32];

  // ---- Q frags for both items (row=l31 query <8 real, k=kg2*8+j)
  bf16x8 qaA = (bf16x8)0, qaB = (bf16x8)0;
  if (l31 < 8) {
    int n = l31;
    int tq = wbase + (n >> 2) * 1024 + ((n >> 1) & 1) * 32 + (n & 1);
    const short* qp = qbuf + (size_t)tq * 192;
    qaA = *(const bf16x8*)(qp + hA * 16 + kg2 * 8);
    qaB = *(const bf16x8*)(qp + hB * 16 + kg2 * 8);
  }

  const unsigned lko = (unsigned)(kg2 * 16);
  const unsigned lvo = (unsigned)((lane & 1) * 16);
  unsigned vbadr = (unsigned)(size_t)((__attribute__((address_space(3))) short*)Vs)
                 + (unsigned)(lkg * 256 + (lrow >> 2) * 32 + (lane & 3) * 8);
  const f32x16 zero16 = (f32x16)0.f;

  // ================= item A: gathers =================
  bf16x8 kfA[7], vvA[7];
  {
    const unsigned ko = (unsigned)(hA * 32) + lko;
    const unsigned vo = (unsigned)(hA * 32) + lvo;
#pragma unroll
    for (int T = 0; T < 7; ++T)
      kfA[T] = *(const bf16x8*)((const char*)kbuf + (unsigned)ti7[T] + ko);
#pragma unroll
    for (int k = 0; k < 7; ++k)
      vvA[k] = *(const bf16x8*)((const char*)vbuf + (unsigned)mv7[k] + vo);
  }

  // ---- A: QK^T + softmax-partial + P store
  float sumA[4] = {0.f, 0.f, 0.f, 0.f};
#pragma unroll
  for (int T = 0; T < 7; ++T) {
    f32x16 c = __builtin_amdgcn_mfma_f32_32x32x16_bf16(qaA, kfA[T], zero16, 0, 0, 0);
#pragma unroll
    for (int r = 0; r < 4; ++r) {
      float sv = c[r];
      if (T == 6 && l31 >= 24) sv = -1e30f;
      float p = exp2f(sv);
      sumA[r] += p;
      Ps[(r + 4 * kg2) * 232 + T * 32 + l31] = f2bf(p);
    }
  }
  float invqA[4];
#pragma unroll
  for (int r = 0; r < 4; ++r) {
    float s = sumA[r];
    s += __shfl_xor(s, 1); s += __shfl_xor(s, 2); s += __shfl_xor(s, 4);
    s += __shfl_xor(s, 8); s += __shfl_xor(s, 16);
    float iv = 1.f / s;
    float oth = __shfl_xor(iv, 32);
    invqA[r] = (lane & 16) ? oth : iv;
  }

  // ================= item B: gathers issued NOW (fly under A's PV) =========
  bf16x8 kfB[7], vvB[7];
  {
    const unsigned ko = (unsigned)(hB * 32) + lko;
    const unsigned vo = (unsigned)(hB * 32) + lvo;
#pragma unroll
    for (int T = 0; T < 7; ++T)
      kfB[T] = *(const bf16x8*)((const char*)kbuf + (unsigned)ti7[T] + ko);
#pragma unroll
    for (int k = 0; k < 7; ++k)
      vvB[k] = *(const bf16x8*)((const char*)vbuf + (unsigned)mv7[k] + vo);
  }

  // ---- A: V -> LDS, PV, store O
  {
#pragma unroll
    for (int k = 0; k < 7; ++k)
      *(bf16x8*)(Vs + ((unsigned)lane + (unsigned)k * 64u) * 8u) = vvA[k];
    asm volatile("s_waitcnt lgkmcnt(0)" ::: "memory");
    __builtin_amdgcn_sched_barrier(0);

    bf16x4 t0[7], t1[7];
#pragma unroll
    for (int T = 0; T < 7; ++T) {
      unsigned a = vbadr + (unsigned)(T * 1024);
      asm volatile("ds_read_b64_tr_b16 %0, %1" : "=v"(t0[T]) : "v"(a));
      asm volatile("ds_read_b64_tr_b16 %0, %1 offset:128" : "=v"(t1[T]) : "v"(a));
    }
    bf16x8 pa[7];
#pragma unroll
    for (int T = 0; T < 7; ++T) {
      pa[T] = (bf16x8)0;
      if (lrow < 8) pa[T] = *(const bf16x8*)(Ps + lrow * 232 + T * 32 + lkg * 8);
    }
    asm volatile("s_waitcnt lgkmcnt(0)" ::: "memory");
    __builtin_amdgcn_sched_barrier(0);
    f32x4 o = {0.f, 0.f, 0.f, 0.f};
#pragma unroll
    for (int T = 0; T < 7; ++T) {
      bf16x8 vf = __builtin_shufflevector(t0[T], t1[T], 0, 1, 2, 3, 4, 5, 6, 7);
      o = __builtin_amdgcn_mfma_f32_16x16x32_bf16(pa[T], vf, o, 0, 0, 0);
    }
    if (lane < 32) {
#pragma unroll
      for (int r = 0; r < 4; ++r) {
        int n = (lane >> 4) * 4 + r;
        int tq = wbase + (n >> 2) * 1024 + ((n >> 1) & 1) * 32 + (n & 1);
        obuf[(size_t)tq * 192 + hA * 16 + lrow] = f2bf(o[r] * invqA[r]);
      }
    }
  }

  // ================= item B: compute (gathers have landed) ==================
  float sumB[4] = {0.f, 0.f, 0.f, 0.f};
#pragma unroll
  for (int T = 0; T < 7; ++T) {
    f32x16 c = __builtin_amdgcn_mfma_f32_32x32x16_bf16(qaB, kfB[T], zero16, 0, 0, 0);
#pragma unroll
    for (int r = 0; r < 4; ++r) {
      float sv = c[r];
      if (T == 6 && l31 >= 24) sv = -1e30f;
      float p = exp2f(sv);
      sumB[r] += p;
      Ps[(r + 4 * kg2) * 232 + T * 32 + l31] = f2bf(p);
    }
  }
  float invqB[4];
#pragma unroll
  for (int r = 0; r < 4; ++r) {
    float s = sumB[r];
    s += __shfl_xor(s, 1); s += __shfl_xor(s, 2); s += __shfl_xor(s, 4);
    s += __shfl_xor(s, 8); s += __shfl_xor(s, 16);
    float iv = 1.f / s;
    float oth = __shfl_xor(iv, 32);
    invqB[r] = (lane & 16) ? oth : iv;
  }
  {
#pragma unroll
    for (int k = 0; k < 7; ++k)
      *(bf16x8*)(Vs + ((unsigned)lane + (unsigned)k * 64u) * 8u) = vvB[k];
    asm volatile("s_waitcnt lgkmcnt(0)" ::: "memory");
    __builtin_amdgcn_sched_barrier(0);

    bf16x4 t0[7], t1[7];
#pragma unroll
    for (int T = 0; T < 7; ++T) {
      unsigned a = vbadr + (unsigned)(T * 1024);
      asm volatile("ds_read_b64_tr_b16 %0, %1" : "=v"(t0[T]) : "v"(a));
      asm volatile("ds_read_b64_tr_b16 %0, %1 offset:128" : "=v"(t1[T]) : "v"(a));
    }
    bf16x8 pa[7];
#pragma unroll
    for (int T = 0; T < 7; ++T) {
      pa[T] = (bf16x8)0;
      if (lrow < 8) pa[T] = *(const bf16x8*)(Ps + lrow * 232 + T * 32 + lkg * 8);
    }
    asm volatile("s_waitcnt lgkmcnt(0)" ::: "memory");
    __builtin_amdgcn_sched_barrier(0);
    f32x4 o = {0.f, 0.f, 0.f, 0.f};
#pragma unroll
    for (int T = 0; T < 7; ++T) {
      bf16x8 vf = __builtin_shufflevector(t0[T], t1[T], 0, 1, 2, 3, 4, 5, 6, 7);
      o = __builtin_amdgcn_mfma_f32_16x16x32_bf16(pa[T], vf, o, 0, 0, 0);
    }
    if (lane < 32) {
#pragma unroll
      for (int r = 0; r < 4; ++r) {
        int n = (lane >> 4) * 4 + r;
        int tq = wbase + (n >> 2) * 1024 + ((n >> 1) & 1) * 32 + (n & 1);
        obuf[(size_t)tq * 192 + hB * 16 + lrow] = f2bf(o[r] * invqB[r]);
      }
    }
  }
}

extern "C" void kernel_launch(void* const* d_in, const int* in_sizes, int n_in,
                              void* d_out, int out_size, void* d_ws, size_t ws_size,
                              hipStream_t stream) {
  const float* x   = (const float*)d_in[0];
  const float* xa  = (const float*)d_in[1];
  const float* n1g = (const float*)d_in[2];
  const float* n1b = (const float*)d_in[3];
  const float* n2g = (const float*)d_in[4];
  const float* n2b = (const float*)d_in[5];
  const float* Wq  = (const float*)d_in[6];
  const float* bq  = (const float*)d_in[7];
  const float* Wkv = (const float*)d_in[8];
  const float* bkv = (const float*)d_in[9];
  const float* Wp  = (const float*)d_in[10];
  const float* bp  = (const float*)d_in[11];
  const float* W1  = (const float*)d_in[12];
  const float* b1  = (const float*)d_in[13];
  const float* W2  = (const float*)d_in[14];
  const float* b2  = (const float*)d_in[15];

  char* wsb = (char*)d_ws;
  const size_t BB = (size_t)TOK * 192 * 2;  // 12.58 MB bf16 token buffer
  short* attn_o = (short*)(wsb + 0 * BB);
  short* xn2    = (short*)(wsb + 1 * BB);               // LN2 out (bf16)
  short* qb     = (short*)(wsb + 2 * BB);               // Q; later hmlp spans qb..kb
  short* kb     = (short*)(wsb + 3 * BB);               // K + ext row TOK
  short* vb     = (short*)(wsb + 4 * BB + 4096);        // V + ext row TOK
  float* x1     = (float*)(wsb + 5 * BB + 8192);        // f32 [TOK][192] (2*BB)
  char* p = wsb + 7 * BB + 16384;
  int* gIdx = (int*)p;            p += (size_t)NWIN * 224 * 4;
  short* wq_p  = (short*)p;       p += 192 * 192 * 2;
  short* wkv_p = (short*)p;       p += 192 * 384 * 2;
  short* wp_p  = (short*)p;       p += 192 * 192 * 2;
  short* w1_p  = (short*)p;       p += 192 * 384 * 2;
  short* w2_p  = (short*)p;       p += 384 * 192 * 2;

  short* hmlp = qb;  // [TOK][384] bf16 spans qb(BB) + kb region

  prep_kernel<<<144 + NWIN + 1, 256, 0, stream>>>(
      Wq, Wkv, Wp, W1, W2, bkv, wq_p, wkv_p, wp_p, w1_p, w2_p,
      kb + (size_t)TOK * 192, vb + (size_t)TOK * 192, gIdx);

  // merged: Q = (LN1(x)@Wq+bq)*0.25*log2e ; K,V = LN1(xa)@Wkv+bkv
  qkv_gemm<<<dim3(512, 3), 256, 0, stream>>>(
      x, xa, wq_p, wkv_p, bq, bkv, n1g, n1b, qb, kb, vb);

  attn_mfma<<<NWIN * 3, 128, 0, stream>>>(qb, kb, vb, gIdx, attn_o);

  // x1 = x + attn_o@Wp+bp ; xn2 = LN2(x1)   (MT=2: 128 rows/block)
  gemm_mfma<EP_RESID_LN, 2, 12, 192, 192><<<dim3(256, 1), 256, 0, stream>>>(
      attn_o, wp_p, bp, x, n2g, n2b, x1, xn2);

  gemm_mfma<EP_GELU, 2, 12, 192, 384><<<dim3(256, 2), 256, 0, stream>>>(
      xn2, w1_p, b1, nullptr, nullptr, nullptr, hmlp, nullptr);
  gemm_mfma<EP_RESID, 2, 6, 384, 192><<<dim3(256, 2), 256, 0, stream>>>(
      hmlp, w2_p, b2, x1, nullptr, nullptr, (float*)d_out, nullptr);
}